// Round 1
// baseline (2743.295 us; speedup 1.0000x reference)
//
#include <hip/hip_runtime.h>

// ---------------- constants ----------------
static constexpr int BM = 64, BN = 64, BK = 16;
static constexpr int SCAN_CHUNK = 1024;

// ---------------- small prep kernels ----------------
__global__ void k_bnprep(const float* __restrict__ g, const float* __restrict__ beta,
                         const float* __restrict__ rm, const float* __restrict__ rv,
                         const float* __restrict__ b, int n,
                         float* __restrict__ scale, float* __restrict__ shift) {
  int i = blockIdx.x * blockDim.x + threadIdx.x;
  if (i < n) {
    float s = g[i] * rsqrtf(rv[i] + 1e-5f);
    scale[i] = s;
    shift[i] = (b[i] - rm[i]) * s + beta[i];
  }
}

__global__ void k_edge_count(const int* __restrict__ dst, int E, int* __restrict__ cnt) {
  int i = blockIdx.x * blockDim.x + threadIdx.x;
  if (i < E) atomicAdd(&cnt[dst[i]], 1);
}

__global__ void k_dinv(const int* __restrict__ cnt, int n, float* __restrict__ dinv) {
  int i = blockIdx.x * blockDim.x + threadIdx.x;
  if (i < n) dinv[i] = rsqrtf(1.0f + (float)cnt[i]);
}

__global__ void k_gcnt(const int* __restrict__ batch, int n, int* __restrict__ gcnt) {
  int i = blockIdx.x * blockDim.x + threadIdx.x;
  if (i < n) atomicAdd(&gcnt[batch[i]], 1);
}

__global__ void k_init_maxu(unsigned* __restrict__ p, int n) {
  int i = blockIdx.x * blockDim.x + threadIdx.x;
  if (i < n) p[i] = 0x007FFFFFu;  // enc(-inf)
}

// ---------------- exclusive scan (3 kernels) ----------------
__global__ void k_chunk_sum(const int* __restrict__ cnt, int n, int* __restrict__ bsum) {
  __shared__ int s[256];
  int base = blockIdx.x * SCAN_CHUNK;
  int t = threadIdx.x;
  int v = 0;
  for (int i = t; i < SCAN_CHUNK; i += 256) {
    int idx = base + i;
    v += (idx < n) ? cnt[idx] : 0;
  }
  s[t] = v;
  __syncthreads();
  for (int o = 128; o > 0; o >>= 1) {
    if (t < o) s[t] += s[t + o];
    __syncthreads();
  }
  if (t == 0) bsum[blockIdx.x] = s[0];
}

__global__ void k_scan_bsum(int* __restrict__ bsum, int nb) {
  if (threadIdx.x == 0 && blockIdx.x == 0) {
    int acc = 0;
    for (int i = 0; i < nb; ++i) { int v = bsum[i]; bsum[i] = acc; acc += v; }
  }
}

__global__ void k_write_rowptr(const int* __restrict__ cnt, int n, const int* __restrict__ bsum,
                               int* __restrict__ rowptr, int E) {
  __shared__ int s[256];
  __shared__ int sx[257];
  int base = blockIdx.x * SCAN_CHUNK;
  int t = threadIdx.x;
  int loc[4];
  int sum = 0;
#pragma unroll
  for (int j = 0; j < 4; ++j) {
    int idx = base + t * 4 + j;
    int c = (idx < n) ? cnt[idx] : 0;
    loc[j] = sum;
    sum += c;
  }
  s[t] = sum;
  __syncthreads();
  if (t == 0) {
    int acc = 0;
    for (int i = 0; i < 256; ++i) { sx[i] = acc; acc += s[i]; }
  }
  __syncthreads();
  int off = bsum[blockIdx.x] + sx[t];
#pragma unroll
  for (int j = 0; j < 4; ++j) {
    int idx = base + t * 4 + j;
    if (idx < n) rowptr[idx] = off + loc[j];
  }
  if (blockIdx.x == 0 && t == 0) rowptr[n] = E;
}

__global__ void k_fill(const int* __restrict__ src, const int* __restrict__ dst, int E,
                       const int* __restrict__ rowptr, int* __restrict__ cursor,
                       const float* __restrict__ dinv, int* __restrict__ col,
                       float* __restrict__ wt) {
  int e = blockIdx.x * blockDim.x + threadIdx.x;
  if (e < E) {
    int d = dst[e], s = src[e];
    int p = atomicAdd(&cursor[d], 1);
    int idx = rowptr[d] + p;
    col[idx] = s;
    wt[idx] = dinv[s] * dinv[d];
  }
}

// ---------------- aggregation: one wave per node ----------------
template <int F>
__global__ __launch_bounds__(256) void k_aggregate(const float* __restrict__ in,
                                                   const int* __restrict__ rowptr,
                                                   const int* __restrict__ col,
                                                   const float* __restrict__ wt,
                                                   const float* __restrict__ dinv, int n,
                                                   float* __restrict__ out) {
  constexpr int NF = (F + 63) / 64;
  int wid = (int)((blockIdx.x * (size_t)blockDim.x + threadIdx.x) >> 6);
  int lane = threadIdx.x & 63;
  if (wid >= n) return;
  float acc[NF];
  float di = dinv[wid];
  float sw = di * di;
#pragma unroll
  for (int j = 0; j < NF; ++j) {
    int f = lane + 64 * j;
    acc[j] = (f < F) ? sw * in[(size_t)wid * F + f] : 0.0f;
  }
  int e0 = rowptr[wid], e1 = rowptr[wid + 1];
  for (int e = e0; e < e1; ++e) {
    int s = col[e];
    float w = wt[e];
    const float* ip = in + (size_t)s * F;
#pragma unroll
    for (int j = 0; j < NF; ++j) {
      int f = lane + 64 * j;
      if (f < F) acc[j] += w * ip[f];
    }
  }
#pragma unroll
  for (int j = 0; j < NF; ++j) {
    int f = lane + 64 * j;
    if (f < F) out[(size_t)wid * F + f] = acc[j];
  }
}

// ---------------- GEMM + fused epilogue ----------------
// EPI 0: v = relu(v*scale[col]+shift[col]) -> C
// EPI 2: v = v + shift[col] (bias); atomic mean/max pooling by graph id
template <int EPI>
__global__ __launch_bounds__(256) void k_gemm(const float* __restrict__ A,
                                              const float* __restrict__ B, int M, int N, int K,
                                              const float* __restrict__ scale,
                                              const float* __restrict__ shift,
                                              float* __restrict__ C,
                                              const int* __restrict__ batch,
                                              float* __restrict__ pool_sum,
                                              unsigned* __restrict__ pool_maxu) {
  __shared__ float As[BM][BK + 1];
  __shared__ float Bs[BK][BN];
  int tid = threadIdx.x;
  int tx = tid & 15, ty = tid >> 4;
  int m0 = blockIdx.y * BM;
  int n0 = blockIdx.x * BN;
  float c[4][4] = {};
  for (int kb = 0; kb < K; kb += BK) {
#pragma unroll
    for (int j = 0; j < 4; ++j) {
      int id = tid + 256 * j;
      int k = id & 15, m = id >> 4;
      int gm = m0 + m, gk = kb + k;
      As[m][k] = (gm < M && gk < K) ? A[(size_t)gm * K + gk] : 0.0f;
    }
#pragma unroll
    for (int j = 0; j < 4; ++j) {
      int id = tid + 256 * j;
      int n = id & 63, k = id >> 6;
      int gk = kb + k;
      Bs[k][n] = (gk < K) ? B[(size_t)gk * N + n0 + n] : 0.0f;
    }
    __syncthreads();
#pragma unroll
    for (int k = 0; k < BK; ++k) {
      float a[4], b[4];
#pragma unroll
      for (int i = 0; i < 4; ++i) a[i] = As[ty * 4 + i][k];
#pragma unroll
      for (int j = 0; j < 4; ++j) b[j] = Bs[k][tx * 4 + j];
#pragma unroll
      for (int i = 0; i < 4; ++i)
#pragma unroll
        for (int j = 0; j < 4; ++j) c[i][j] = fmaf(a[i], b[j], c[i][j]);
    }
    __syncthreads();
  }
#pragma unroll
  for (int i = 0; i < 4; ++i) {
    int row = m0 + ty * 4 + i;
    if (row >= M) continue;
    int g = 0;
    if (EPI == 2) g = batch[row];
#pragma unroll
    for (int j = 0; j < 4; ++j) {
      int colx = n0 + tx * 4 + j;
      float v = c[i][j];
      if (EPI == 0) {
        v = fmaxf(fmaf(v, scale[colx], shift[colx]), 0.0f);
        C[(size_t)row * N + colx] = v;
      } else {
        v += shift[colx];
        atomicAdd(&pool_sum[(size_t)g * N + colx], v);
        unsigned ub = __float_as_uint(v);
        ub = (ub & 0x80000000u) ? ~ub : (ub | 0x80000000u);
        atomicMax(&pool_maxu[(size_t)g * N + colx], ub);
      }
    }
  }
}

__global__ void k_finalize(const float* __restrict__ pool_sum,
                           const unsigned* __restrict__ pool_maxu,
                           const int* __restrict__ gcnt, int total, int N,
                           float* __restrict__ out) {
  int i = blockIdx.x * blockDim.x + threadIdx.x;
  if (i < total) {
    int g = i / N;
    float mean = pool_sum[i] / fmaxf((float)gcnt[g], 1.0f);
    unsigned u = pool_maxu[i];
    float mx = (u & 0x80000000u) ? __uint_as_float(u ^ 0x80000000u) : __uint_as_float(~u);
    out[i] = mean + mx;
  }
}

// ---------------- host launch ----------------
extern "C" void kernel_launch(void* const* d_in, const int* in_sizes, int n_in, void* d_out,
                              int out_size, void* d_ws, size_t ws_size, hipStream_t stream) {
  const float* x    = (const float*)d_in[0];
  const int* edge   = (const int*)d_in[1];
  const int* batch  = (const int*)d_in[2];
  const float* W1   = (const float*)d_in[3];
  const float* b1   = (const float*)d_in[4];
  const float* g1   = (const float*)d_in[5];
  const float* be1  = (const float*)d_in[6];
  const float* rm1  = (const float*)d_in[7];
  const float* rv1  = (const float*)d_in[8];
  const float* W2   = (const float*)d_in[9];
  const float* b2   = (const float*)d_in[10];
  const float* g2   = (const float*)d_in[11];
  const float* be2  = (const float*)d_in[12];
  const float* rm2  = (const float*)d_in[13];
  const float* rv2  = (const float*)d_in[14];
  const float* W3   = (const float*)d_in[15];
  const float* b3   = (const float*)d_in[16];

  const int NN = in_sizes[2];       // 100000 nodes
  const int E  = in_sizes[1] / 2;   // 1600000 edges
  const int F0 = in_sizes[0] / NN;  // 74
  const int F1 = in_sizes[4];       // 256
  const int F3 = in_sizes[16];      // 384
  const int NG = out_size / F3;     // 2048
  const int* srcv = edge;
  const int* dstv = edge + E;

  char* p = (char*)d_ws;
  auto carve = [&](size_t bytes) -> char* {
    char* r = p;
    p += (bytes + 255) & ~(size_t)255;
    return r;
  };
  float* dinv      = (float*)carve((size_t)NN * 4);
  int* cnt         = (int*)carve((size_t)NN * 4);
  int* rowptr      = (int*)carve((size_t)(NN + 1) * 4);
  int* cursor      = (int*)carve((size_t)NN * 4);
  int* bsum        = (int*)carve(4096);
  int* col         = (int*)carve((size_t)E * 4);
  float* wt        = (float*)carve((size_t)E * 4);
  float* scale1    = (float*)carve((size_t)F1 * 4);
  float* shift1    = (float*)carve((size_t)F1 * 4);
  float* scale2    = (float*)carve((size_t)F1 * 4);
  float* shift2    = (float*)carve((size_t)F1 * 4);
  int* gcnt        = (int*)carve((size_t)NG * 4);
  float* pool_sum  = (float*)carve((size_t)NG * F3 * 4);
  unsigned* pool_m = (unsigned*)carve((size_t)NG * F3 * 4);
  float* agg       = (float*)carve((size_t)NN * F1 * 4);
  float* h         = (float*)carve((size_t)NN * F1 * 4);
  (void)ws_size; (void)n_in;

  // init
  hipMemsetAsync(cnt, 0, (size_t)NN * 4, stream);
  hipMemsetAsync(cursor, 0, (size_t)NN * 4, stream);
  hipMemsetAsync(gcnt, 0, (size_t)NG * 4, stream);
  hipMemsetAsync(pool_sum, 0, (size_t)NG * F3 * 4, stream);
  k_init_maxu<<<(NG * F3 + 255) / 256, 256, 0, stream>>>(pool_m, NG * F3);
  k_bnprep<<<1, 256, 0, stream>>>(g1, be1, rm1, rv1, b1, F1, scale1, shift1);
  k_bnprep<<<1, 256, 0, stream>>>(g2, be2, rm2, rv2, b2, F1, scale2, shift2);
  k_gcnt<<<(NN + 255) / 256, 256, 0, stream>>>(batch, NN, gcnt);

  // CSR build
  k_edge_count<<<(E + 255) / 256, 256, 0, stream>>>(dstv, E, cnt);
  k_dinv<<<(NN + 255) / 256, 256, 0, stream>>>(cnt, NN, dinv);
  int nchunks = (NN + SCAN_CHUNK - 1) / SCAN_CHUNK;
  k_chunk_sum<<<nchunks, 256, 0, stream>>>(cnt, NN, bsum);
  k_scan_bsum<<<1, 64, 0, stream>>>(bsum, nchunks);
  k_write_rowptr<<<nchunks, 256, 0, stream>>>(cnt, NN, bsum, rowptr, E);
  k_fill<<<(E + 255) / 256, 256, 0, stream>>>(srcv, dstv, E, rowptr, cursor, dinv, col, wt);

  dim3 blk(256);
  int aggBlocks = (NN + 3) / 4;  // 4 waves (nodes) per 256-thread block

  // Layer 1: agg over x (74) -> GEMM(74->256) + bn1 + relu -> h
  k_aggregate<74><<<aggBlocks, blk, 0, stream>>>(x, rowptr, col, wt, dinv, NN, agg);
  {
    dim3 grid(F1 / BN, (NN + BM - 1) / BM);
    k_gemm<0><<<grid, blk, 0, stream>>>(agg, W1, NN, F1, F0, scale1, shift1, h, nullptr,
                                        nullptr, nullptr);
  }
  // Layer 2
  k_aggregate<256><<<aggBlocks, blk, 0, stream>>>(h, rowptr, col, wt, dinv, NN, agg);
  {
    dim3 grid(F1 / BN, (NN + BM - 1) / BM);
    k_gemm<0><<<grid, blk, 0, stream>>>(agg, W2, NN, F1, F1, scale2, shift2, h, nullptr,
                                        nullptr, nullptr);
  }
  // Layer 3: agg -> GEMM(256->384) + bias, fused pooling
  k_aggregate<256><<<aggBlocks, blk, 0, stream>>>(h, rowptr, col, wt, dinv, NN, agg);
  {
    dim3 grid(F3 / BN, (NN + BM - 1) / BM);
    k_gemm<2><<<grid, blk, 0, stream>>>(agg, W3, NN, F3, F1, nullptr, b3, nullptr, batch,
                                        pool_sum, pool_m);
  }
  k_finalize<<<(NG * F3 + 255) / 256, 256, 0, stream>>>(pool_sum, pool_m, gcnt, NG * F3, F3,
                                                        (float*)d_out);
}

// Round 2
// 1575.817 us; speedup vs baseline: 1.7409x; 1.7409x over previous
//
#include <hip/hip_runtime.h>

// ---------------- constants ----------------
static constexpr int BM = 128, BN = 64, BK = 16;
static constexpr int SCAN_CHUNK = 1024;

// ---------------- small prep kernels ----------------
__global__ void k_bnprep(const float* __restrict__ g, const float* __restrict__ beta,
                         const float* __restrict__ rm, const float* __restrict__ rv,
                         const float* __restrict__ b, int n,
                         float* __restrict__ scale, float* __restrict__ shift) {
  int i = blockIdx.x * blockDim.x + threadIdx.x;
  if (i < n) {
    float s = g[i] * rsqrtf(rv[i] + 1e-5f);
    scale[i] = s;
    shift[i] = (b[i] - rm[i]) * s + beta[i];
  }
}

__global__ void k_edge_count(const int* __restrict__ dst, int E, int* __restrict__ cnt) {
  int i = blockIdx.x * blockDim.x + threadIdx.x;
  if (i < E) atomicAdd(&cnt[dst[i]], 1);
}

__global__ void k_dinv(const int* __restrict__ cnt, int n, float* __restrict__ dinv) {
  int i = blockIdx.x * blockDim.x + threadIdx.x;
  if (i < n) dinv[i] = rsqrtf(1.0f + (float)cnt[i]);
}

__global__ void k_gcnt(const int* __restrict__ batch, int n, int* __restrict__ gcnt) {
  int i = blockIdx.x * blockDim.x + threadIdx.x;
  if (i < n) atomicAdd(&gcnt[batch[i]], 1);
}

__global__ void k_init_maxu(unsigned* __restrict__ p, int n) {
  int i = blockIdx.x * blockDim.x + threadIdx.x;
  if (i < n) p[i] = 0x007FFFFFu;  // enc(-inf)
}

__global__ void k_padW(const float* __restrict__ W, int KN, int KpN, float* __restrict__ Wp) {
  int i = blockIdx.x * blockDim.x + threadIdx.x;
  if (i < KpN) Wp[i] = (i < KN) ? W[i] : 0.0f;
}

// ---------------- exclusive scan (3 kernels) ----------------
__global__ void k_chunk_sum(const int* __restrict__ cnt, int n, int* __restrict__ bsum) {
  __shared__ int s[256];
  int base = blockIdx.x * SCAN_CHUNK;
  int t = threadIdx.x;
  int v = 0;
  for (int i = t; i < SCAN_CHUNK; i += 256) {
    int idx = base + i;
    v += (idx < n) ? cnt[idx] : 0;
  }
  s[t] = v;
  __syncthreads();
  for (int o = 128; o > 0; o >>= 1) {
    if (t < o) s[t] += s[t + o];
    __syncthreads();
  }
  if (t == 0) bsum[blockIdx.x] = s[0];
}

__global__ void k_scan_bsum(int* __restrict__ bsum, int nb) {
  if (threadIdx.x == 0 && blockIdx.x == 0) {
    int acc = 0;
    for (int i = 0; i < nb; ++i) { int v = bsum[i]; bsum[i] = acc; acc += v; }
  }
}

__global__ void k_write_rowptr(const int* __restrict__ cnt, int n, const int* __restrict__ bsum,
                               int* __restrict__ rowptr, int E) {
  __shared__ int s[256];
  __shared__ int sx[257];
  int base = blockIdx.x * SCAN_CHUNK;
  int t = threadIdx.x;
  int loc[4];
  int sum = 0;
#pragma unroll
  for (int j = 0; j < 4; ++j) {
    int idx = base + t * 4 + j;
    int c = (idx < n) ? cnt[idx] : 0;
    loc[j] = sum;
    sum += c;
  }
  s[t] = sum;
  __syncthreads();
  if (t == 0) {
    int acc = 0;
    for (int i = 0; i < 256; ++i) { sx[i] = acc; acc += s[i]; }
  }
  __syncthreads();
  int off = bsum[blockIdx.x] + sx[t];
#pragma unroll
  for (int j = 0; j < 4; ++j) {
    int idx = base + t * 4 + j;
    if (idx < n) rowptr[idx] = off + loc[j];
  }
  if (blockIdx.x == 0 && t == 0) rowptr[n] = E;
}

__global__ void k_fill(const int* __restrict__ src, const int* __restrict__ dst, int E,
                       const int* __restrict__ rowptr, int* __restrict__ cursor,
                       const float* __restrict__ dinv, int* __restrict__ col,
                       float* __restrict__ wt) {
  int e = blockIdx.x * blockDim.x + threadIdx.x;
  if (e < E) {
    int d = dst[e], s = src[e];
    int p = atomicAdd(&cursor[d], 1);
    int idx = rowptr[d] + p;
    col[idx] = s;
    wt[idx] = dinv[s] * dinv[d];
  }
}

// ---------------- aggregation ----------------
// F=74 input (x), output zero-padded to stride 80.
__global__ __launch_bounds__(256) void k_aggregate74(const float* __restrict__ in,
                                                     const int* __restrict__ rowptr,
                                                     const int* __restrict__ col,
                                                     const float* __restrict__ wt,
                                                     const float* __restrict__ dinv, int n,
                                                     float* __restrict__ out) {
  int wid = (int)((blockIdx.x * (size_t)blockDim.x + threadIdx.x) >> 6);
  int lane = threadIdx.x & 63;
  if (wid >= n) return;
  float di = dinv[wid];
  float sw = di * di;
  const float* sp = in + (size_t)wid * 74;
  float acc0 = sw * sp[lane];
  float acc1 = (lane < 10) ? sw * sp[64 + lane] : 0.0f;
  int e0 = rowptr[wid], e1 = rowptr[wid + 1];
  for (int e = e0; e < e1; ++e) {
    int s = col[e];
    float w = wt[e];
    const float* ip = in + (size_t)s * 74;
    acc0 = fmaf(w, ip[lane], acc0);
    if (lane < 10) acc1 = fmaf(w, ip[64 + lane], acc1);
  }
  out[(size_t)wid * 80 + lane] = acc0;
  if (lane < 16) out[(size_t)wid * 80 + 64 + lane] = (lane < 10) ? acc1 : 0.0f;
}

// F=256, vectorized float4 gathers.
__global__ __launch_bounds__(256) void k_aggregate256(const float* __restrict__ in,
                                                      const int* __restrict__ rowptr,
                                                      const int* __restrict__ col,
                                                      const float* __restrict__ wt,
                                                      const float* __restrict__ dinv, int n,
                                                      float* __restrict__ out) {
  int wid = (int)((blockIdx.x * (size_t)blockDim.x + threadIdx.x) >> 6);
  int lane = threadIdx.x & 63;
  if (wid >= n) return;
  float di = dinv[wid];
  float sw = di * di;
  float4 acc = ((const float4*)(in + (size_t)wid * 256))[lane];
  acc.x *= sw; acc.y *= sw; acc.z *= sw; acc.w *= sw;
  int e0 = rowptr[wid], e1 = rowptr[wid + 1];
  for (int e = e0; e < e1; ++e) {
    int s = col[e];
    float w = wt[e];
    float4 v = ((const float4*)(in + (size_t)s * 256))[lane];
    acc.x = fmaf(w, v.x, acc.x);
    acc.y = fmaf(w, v.y, acc.y);
    acc.z = fmaf(w, v.z, acc.z);
    acc.w = fmaf(w, v.w, acc.w);
  }
  ((float4*)(out + (size_t)wid * 256))[lane] = acc;
}

// ---------------- GEMM + fused epilogue ----------------
// A: [M x lda] (K <= lda, K%16==0), B: [K x N]. 128x64 tile, 8x4 per thread.
// EPI 0: v = relu(v*scale[col]+shift[col]) -> C
// EPI 2: v = v + shift[col]; per-thread graph-run reduction, then atomic pool
template <int EPI>
__global__ __launch_bounds__(256) void k_gemm(const float* __restrict__ A, int lda,
                                              const float* __restrict__ B, int M, int N, int K,
                                              const float* __restrict__ scale,
                                              const float* __restrict__ shift,
                                              float* __restrict__ C,
                                              const int* __restrict__ batch,
                                              float* __restrict__ pool_sum,
                                              unsigned* __restrict__ pool_maxu) {
  __shared__ float Ast[BK][BM];  // k-major: inner reads are float4 over m
  __shared__ float Bs[BK][BN];
  const int tid = threadIdx.x;
  const int tx = tid & 15, ty = tid >> 4;
  const int m0 = blockIdx.y * BM;
  const int n0 = blockIdx.x * BN;
  // staging coords
  const int am = tid >> 1;         // 0..127
  const int ak = (tid & 1) * 8;    // 0 or 8
  const int gm = m0 + am;
  const int bk = tid >> 4;         // 0..15
  const int bn = (tid & 15) * 4;
  float c[8][4] = {};

  for (int kb = 0; kb < K; kb += BK) {
    // A tile: 128x16, each thread 8 floats of one row (two float4)
    if (gm < M) {
      const float* ap = A + (size_t)gm * lda + kb + ak;
      float4 a0 = *(const float4*)ap;
      float4 a1 = *(const float4*)(ap + 4);
      Ast[ak + 0][am] = a0.x; Ast[ak + 1][am] = a0.y;
      Ast[ak + 2][am] = a0.z; Ast[ak + 3][am] = a0.w;
      Ast[ak + 4][am] = a1.x; Ast[ak + 5][am] = a1.y;
      Ast[ak + 6][am] = a1.z; Ast[ak + 7][am] = a1.w;
    } else {
#pragma unroll
      for (int q = 0; q < 8; ++q) Ast[ak + q][am] = 0.0f;
    }
    // B tile: 16x64, one float4 per thread
    {
      float4 b4 = *(const float4*)&B[(size_t)(kb + bk) * N + n0 + bn];
      *(float4*)&Bs[bk][bn] = b4;
    }
    __syncthreads();
#pragma unroll
    for (int k = 0; k < BK; ++k) {
      float a[8], b[4];
      *(float4*)&a[0] = *(const float4*)&Ast[k][ty * 8];
      *(float4*)&a[4] = *(const float4*)&Ast[k][ty * 8 + 4];
      *(float4*)&b[0] = *(const float4*)&Bs[k][tx * 4];
#pragma unroll
      for (int i = 0; i < 8; ++i)
#pragma unroll
        for (int j = 0; j < 4; ++j) c[i][j] = fmaf(a[i], b[j], c[i][j]);
    }
    __syncthreads();
  }

  float s4[4], sh4[4];
#pragma unroll
  for (int j = 0; j < 4; ++j) {
    if (EPI == 0) s4[j] = scale[n0 + tx * 4 + j];
    sh4[j] = shift[n0 + tx * 4 + j];
  }
  if (EPI == 0) {
#pragma unroll
    for (int i = 0; i < 8; ++i) {
      int row = m0 + ty * 8 + i;
      if (row >= M) break;
      float4 o;
      o.x = fmaxf(fmaf(c[i][0], s4[0], sh4[0]), 0.0f);
      o.y = fmaxf(fmaf(c[i][1], s4[1], sh4[1]), 0.0f);
      o.z = fmaxf(fmaf(c[i][2], s4[2], sh4[2]), 0.0f);
      o.w = fmaxf(fmaf(c[i][3], s4[3], sh4[3]), 0.0f);
      *(float4*)&C[(size_t)row * N + n0 + tx * 4] = o;
    }
  } else {
    // per-thread graph-run reduction over 8 consecutive rows (batch sorted)
    int i = 0;
    while (i < 8) {
      int row = m0 + ty * 8 + i;
      if (row >= M) break;
      int g = batch[row];
      float sm[4], mx[4];
#pragma unroll
      for (int j = 0; j < 4; ++j) {
        float v = c[i][j] + sh4[j];
        sm[j] = v; mx[j] = v;
      }
      ++i;
      while (i < 8) {
        int r2 = m0 + ty * 8 + i;
        if (r2 >= M || batch[r2] != g) break;
#pragma unroll
        for (int j = 0; j < 4; ++j) {
          float v = c[i][j] + sh4[j];
          sm[j] += v; mx[j] = fmaxf(mx[j], v);
        }
        ++i;
      }
#pragma unroll
      for (int j = 0; j < 4; ++j) {
        int colx = n0 + tx * 4 + j;
        atomicAdd(&pool_sum[(size_t)g * N + colx], sm[j]);
        unsigned ub = __float_as_uint(mx[j]);
        ub = (ub & 0x80000000u) ? ~ub : (ub | 0x80000000u);
        atomicMax(&pool_maxu[(size_t)g * N + colx], ub);
      }
    }
  }
}

__global__ void k_finalize(const float* __restrict__ pool_sum,
                           const unsigned* __restrict__ pool_maxu,
                           const int* __restrict__ gcnt, int total, int N,
                           float* __restrict__ out) {
  int i = blockIdx.x * blockDim.x + threadIdx.x;
  if (i < total) {
    int g = i / N;
    float mean = pool_sum[i] / fmaxf((float)gcnt[g], 1.0f);
    unsigned u = pool_maxu[i];
    float mx = (u & 0x80000000u) ? __uint_as_float(u ^ 0x80000000u) : __uint_as_float(~u);
    out[i] = mean + mx;
  }
}

// ---------------- host launch ----------------
extern "C" void kernel_launch(void* const* d_in, const int* in_sizes, int n_in, void* d_out,
                              int out_size, void* d_ws, size_t ws_size, hipStream_t stream) {
  const float* x    = (const float*)d_in[0];
  const int* edge   = (const int*)d_in[1];
  const int* batch  = (const int*)d_in[2];
  const float* W1   = (const float*)d_in[3];
  const float* b1   = (const float*)d_in[4];
  const float* g1   = (const float*)d_in[5];
  const float* be1  = (const float*)d_in[6];
  const float* rm1  = (const float*)d_in[7];
  const float* rv1  = (const float*)d_in[8];
  const float* W2   = (const float*)d_in[9];
  const float* b2   = (const float*)d_in[10];
  const float* g2   = (const float*)d_in[11];
  const float* be2  = (const float*)d_in[12];
  const float* rm2  = (const float*)d_in[13];
  const float* rv2  = (const float*)d_in[14];
  const float* W3   = (const float*)d_in[15];
  const float* b3   = (const float*)d_in[16];

  const int NN = in_sizes[2];       // 100000
  const int E  = in_sizes[1] / 2;   // 1600000
  const int F0 = in_sizes[0] / NN;  // 74
  const int F1 = in_sizes[4];       // 256
  const int F3 = in_sizes[16];      // 384
  const int NG = out_size / F3;     // 2048
  const int K0p = 80;               // padded K for layer 1
  const int* srcv = edge;
  const int* dstv = edge + E;

  char* p = (char*)d_ws;
  auto carve = [&](size_t bytes) -> char* {
    char* r = p;
    p += (bytes + 255) & ~(size_t)255;
    return r;
  };
  float* dinv      = (float*)carve((size_t)NN * 4);
  int* cnt         = (int*)carve((size_t)NN * 4);
  int* rowptr      = (int*)carve((size_t)(NN + 1) * 4);
  int* cursor      = (int*)carve((size_t)NN * 4);
  int* bsum        = (int*)carve(4096);
  int* col         = (int*)carve((size_t)E * 4);
  float* wt        = (float*)carve((size_t)E * 4);
  float* scale1    = (float*)carve((size_t)F1 * 4);
  float* shift1    = (float*)carve((size_t)F1 * 4);
  float* scale2    = (float*)carve((size_t)F1 * 4);
  float* shift2    = (float*)carve((size_t)F1 * 4);
  float* W1p       = (float*)carve((size_t)K0p * F1 * 4);
  int* gcnt        = (int*)carve((size_t)NG * 4);
  float* pool_sum  = (float*)carve((size_t)NG * F3 * 4);
  unsigned* pool_m = (unsigned*)carve((size_t)NG * F3 * 4);
  float* agg       = (float*)carve((size_t)NN * F1 * 4);  // also layer-1 agg (stride 80)
  float* h         = (float*)carve((size_t)NN * F1 * 4);
  (void)ws_size; (void)n_in; (void)F0;

  // init
  hipMemsetAsync(cnt, 0, (size_t)NN * 4, stream);
  hipMemsetAsync(cursor, 0, (size_t)NN * 4, stream);
  hipMemsetAsync(gcnt, 0, (size_t)NG * 4, stream);
  hipMemsetAsync(pool_sum, 0, (size_t)NG * F3 * 4, stream);
  k_init_maxu<<<(NG * F3 + 255) / 256, 256, 0, stream>>>(pool_m, NG * F3);
  k_bnprep<<<1, 256, 0, stream>>>(g1, be1, rm1, rv1, b1, F1, scale1, shift1);
  k_bnprep<<<1, 256, 0, stream>>>(g2, be2, rm2, rv2, b2, F1, scale2, shift2);
  k_gcnt<<<(NN + 255) / 256, 256, 0, stream>>>(batch, NN, gcnt);
  k_padW<<<(K0p * F1 + 255) / 256, 256, 0, stream>>>(W1, 74 * F1, K0p * F1, W1p);

  // CSR build
  k_edge_count<<<(E + 255) / 256, 256, 0, stream>>>(dstv, E, cnt);
  k_dinv<<<(NN + 255) / 256, 256, 0, stream>>>(cnt, NN, dinv);
  int nchunks = (NN + SCAN_CHUNK - 1) / SCAN_CHUNK;
  k_chunk_sum<<<nchunks, 256, 0, stream>>>(cnt, NN, bsum);
  k_scan_bsum<<<1, 64, 0, stream>>>(bsum, nchunks);
  k_write_rowptr<<<nchunks, 256, 0, stream>>>(cnt, NN, bsum, rowptr, E);
  k_fill<<<(E + 255) / 256, 256, 0, stream>>>(srcv, dstv, E, rowptr, cursor, dinv, col, wt);

  dim3 blk(256);
  int aggBlocks = (NN + 3) / 4;
  int gy = (NN + BM - 1) / BM;

  // Layer 1: agg(x,74 -> stride 80) -> GEMM(80->256) + bn1 + relu -> h
  k_aggregate74<<<aggBlocks, blk, 0, stream>>>(x, rowptr, col, wt, dinv, NN, agg);
  {
    dim3 grid(F1 / BN, gy);
    k_gemm<0><<<grid, blk, 0, stream>>>(agg, K0p, W1p, NN, F1, K0p, scale1, shift1, h,
                                        nullptr, nullptr, nullptr);
  }
  // Layer 2
  k_aggregate256<<<aggBlocks, blk, 0, stream>>>(h, rowptr, col, wt, dinv, NN, agg);
  {
    dim3 grid(F1 / BN, gy);
    k_gemm<0><<<grid, blk, 0, stream>>>(agg, F1, W2, NN, F1, F1, scale2, shift2, h,
                                        nullptr, nullptr, nullptr);
  }
  // Layer 3: agg -> GEMM(256->384) + bias, fused run-reduced pooling
  k_aggregate256<<<aggBlocks, blk, 0, stream>>>(h, rowptr, col, wt, dinv, NN, agg);
  {
    dim3 grid(F3 / BN, gy);
    k_gemm<2><<<grid, blk, 0, stream>>>(agg, F1, W3, NN, F3, F1, nullptr, b3, nullptr,
                                        batch, pool_sum, pool_m);
  }
  k_finalize<<<(NG * F3 + 255) / 256, 256, 0, stream>>>(pool_sum, pool_m, gcnt, NG * F3, F3,
                                                        (float*)d_out);
}

// Round 5
// 1017.447 us; speedup vs baseline: 2.6963x; 1.5488x over previous
//
#include <hip/hip_runtime.h>

// ---------------- types & helpers ----------------
typedef __bf16 bf16x8 __attribute__((ext_vector_type(8)));
typedef float f32x4 __attribute__((ext_vector_type(4)));
typedef unsigned short ushort4v __attribute__((ext_vector_type(4)));
typedef unsigned short ushort8v __attribute__((ext_vector_type(8)));

__device__ __forceinline__ unsigned short f2b(float f) {
  unsigned u = __float_as_uint(f);
  unsigned r = u + 0x7FFFu + ((u >> 16) & 1u);
  return (unsigned short)(r >> 16);
}
__device__ __forceinline__ float b2f(unsigned short v) {
  return __uint_as_float(((unsigned)v) << 16);
}

static constexpr int SCAN_CHUNK = 1024;

// ---------------- small prep kernels ----------------
__global__ void k_bnprep(const float* __restrict__ g, const float* __restrict__ beta,
                         const float* __restrict__ rm, const float* __restrict__ rv,
                         const float* __restrict__ b, int n,
                         float* __restrict__ scale, float* __restrict__ shift) {
  int i = blockIdx.x * blockDim.x + threadIdx.x;
  if (i < n) {
    float s = g[i] * rsqrtf(rv[i] + 1e-5f);
    scale[i] = s;
    shift[i] = (b[i] - rm[i]) * s + beta[i];
  }
}

__global__ void k_edge_count(const int* __restrict__ dst, int E, int* __restrict__ cnt) {
  int i = blockIdx.x * blockDim.x + threadIdx.x;
  if (i < E) atomicAdd(&cnt[dst[i]], 1);
}

__global__ void k_dinv(const int* __restrict__ cnt, int n, float* __restrict__ dinv) {
  int i = blockIdx.x * blockDim.x + threadIdx.x;
  if (i < n) dinv[i] = rsqrtf(1.0f + (float)cnt[i]);
}

// W [K][N] f32 -> Wt [N][Kp] bf16 (zero-padded K..Kp)
__global__ void k_wt(const float* __restrict__ W, int K, int N, int Kp,
                     unsigned short* __restrict__ Wt) {
  int idx = blockIdx.x * blockDim.x + threadIdx.x;
  if (idx >= N * Kp) return;
  int n = idx / Kp, k = idx - n * Kp;
  Wt[idx] = f2b(k < K ? W[(size_t)k * N + n] : 0.0f);
}

// graph boundaries (batch sorted)
__global__ void k_gbounds(const int* __restrict__ batch, int n, int* __restrict__ gstart,
                          int* __restrict__ gend) {
  int i = blockIdx.x * blockDim.x + threadIdx.x;
  if (i >= n) return;
  int g = batch[i];
  if (i == 0 || batch[i - 1] != g) gstart[g] = i;
  if (i == n - 1 || batch[i + 1] != g) gend[g] = i + 1;
}

// ---------------- exclusive scan (3 kernels) ----------------
__global__ void k_chunk_sum(const int* __restrict__ cnt, int n, int* __restrict__ bsum) {
  __shared__ int s[256];
  int base = blockIdx.x * SCAN_CHUNK;
  int t = threadIdx.x;
  int v = 0;
  for (int i = t; i < SCAN_CHUNK; i += 256) {
    int idx = base + i;
    v += (idx < n) ? cnt[idx] : 0;
  }
  s[t] = v;
  __syncthreads();
  for (int o = 128; o > 0; o >>= 1) {
    if (t < o) s[t] += s[t + o];
    __syncthreads();
  }
  if (t == 0) bsum[blockIdx.x] = s[0];
}

__global__ void k_scan_bsum(int* __restrict__ bsum, int nb) {
  if (threadIdx.x == 0 && blockIdx.x == 0) {
    int acc = 0;
    for (int i = 0; i < nb; ++i) { int v = bsum[i]; bsum[i] = acc; acc += v; }
  }
}

__global__ void k_write_rowptr(const int* __restrict__ cnt, int n, const int* __restrict__ bsum,
                               int* __restrict__ rowptr, int E) {
  __shared__ int s[256];
  __shared__ int sx[257];
  int base = blockIdx.x * SCAN_CHUNK;
  int t = threadIdx.x;
  int loc[4];
  int sum = 0;
#pragma unroll
  for (int j = 0; j < 4; ++j) {
    int idx = base + t * 4 + j;
    int c = (idx < n) ? cnt[idx] : 0;
    loc[j] = sum;
    sum += c;
  }
  s[t] = sum;
  __syncthreads();
  if (t == 0) {
    int acc = 0;
    for (int i = 0; i < 256; ++i) { sx[i] = acc; acc += s[i]; }
  }
  __syncthreads();
  int off = bsum[blockIdx.x] + sx[t];
#pragma unroll
  for (int j = 0; j < 4; ++j) {
    int idx = base + t * 4 + j;
    if (idx < n) rowptr[idx] = off + loc[j];
  }
  if (blockIdx.x == 0 && t == 0) rowptr[n] = E;
}

__global__ void k_fill(const int* __restrict__ src, const int* __restrict__ dst, int E,
                       const int* __restrict__ rowptr, int* __restrict__ cursor,
                       const float* __restrict__ dinv, int* __restrict__ col,
                       float* __restrict__ wt) {
  int e = blockIdx.x * blockDim.x + threadIdx.x;
  if (e < E) {
    int d = dst[e], s = src[e];
    int p = atomicAdd(&cursor[d], 1);
    int idx = rowptr[d] + p;
    col[idx] = s;
    wt[idx] = dinv[s] * dinv[d];
  }
}

// ---------------- aggregation ----------------
// layer 1: x f32 [n][74] -> agg bf16 [n][128] (zero pad 74..127)
__global__ __launch_bounds__(256) void k_aggregate74(const float* __restrict__ in,
                                                     const int* __restrict__ rowptr,
                                                     const int* __restrict__ col,
                                                     const float* __restrict__ wt,
                                                     const float* __restrict__ dinv, int n,
                                                     unsigned short* __restrict__ out) {
  int wid = (int)((blockIdx.x * (size_t)blockDim.x + threadIdx.x) >> 6);
  int lane = threadIdx.x & 63;
  if (wid >= n) return;
  float di = dinv[wid];
  float sw = di * di;
  const float* sp = in + (size_t)wid * 74;
  float acc0 = sw * sp[lane];
  float acc1 = (lane < 10) ? sw * sp[64 + lane] : 0.0f;
  int e0 = rowptr[wid], e1 = rowptr[wid + 1];
  for (int e = e0; e < e1; ++e) {
    int s = col[e];
    float w = wt[e];
    const float* ip = in + (size_t)s * 74;
    acc0 = fmaf(w, ip[lane], acc0);
    if (lane < 10) acc1 = fmaf(w, ip[64 + lane], acc1);
  }
  out[(size_t)wid * 128 + lane] = f2b(acc0);
  out[(size_t)wid * 128 + 64 + lane] = (lane < 10) ? f2b(acc1) : (unsigned short)0;
}

// F=256 bf16 in/out, ushort4 per lane
__global__ __launch_bounds__(256) void k_aggregate256(const unsigned short* __restrict__ in,
                                                      const int* __restrict__ rowptr,
                                                      const int* __restrict__ col,
                                                      const float* __restrict__ wt,
                                                      const float* __restrict__ dinv, int n,
                                                      unsigned short* __restrict__ out) {
  int wid = (int)((blockIdx.x * (size_t)blockDim.x + threadIdx.x) >> 6);
  int lane = threadIdx.x & 63;
  if (wid >= n) return;
  float di = dinv[wid];
  float sw = di * di;
  ushort4v sv = *(const ushort4v*)(in + (size_t)wid * 256 + lane * 4);
  float acc[4];
#pragma unroll
  for (int j = 0; j < 4; ++j) acc[j] = sw * b2f(sv[j]);
  int e0 = rowptr[wid], e1 = rowptr[wid + 1];
  for (int e = e0; e < e1; ++e) {
    int s = col[e];
    float w = wt[e];
    ushort4v v = *(const ushort4v*)(in + (size_t)s * 256 + lane * 4);
#pragma unroll
    for (int j = 0; j < 4; ++j) acc[j] = fmaf(w, b2f(v[j]), acc[j]);
  }
  ushort4v o;
#pragma unroll
  for (int j = 0; j < 4; ++j) o[j] = f2b(acc[j]);
  *(ushort4v*)(out + (size_t)wid * 256 + lane * 4) = o;
}

// ---------------- bf16 MFMA GEMM ----------------
// A [M][K] bf16, Bt [N][K] bf16 (pre-transposed weights). K % 64 == 0.
// 128x64 tile, 4 waves in 2x2 (wave tile 64x32), mfma 16x16x32.
// EPI 0: relu(v*scale+shift) -> C bf16 ; EPI 1: v + shift -> C bf16
template <int EPI>
__global__ __launch_bounds__(256) void k_gemm_mfma(const unsigned short* __restrict__ A,
                                                   const unsigned short* __restrict__ Bt,
                                                   int M, int N, int K,
                                                   const float* __restrict__ scale,
                                                   const float* __restrict__ shift,
                                                   unsigned short* __restrict__ C) {
  __shared__ __align__(16) unsigned short Ast[128 * 64];
  __shared__ __align__(16) unsigned short Bst[64 * 64];
  const int t = threadIdx.x;
  const int lane = t & 63;
  const int wid = t >> 6;
  const int wm = wid >> 1, wn = wid & 1;
  const int lr = lane >> 4, lc = lane & 15;
  const int m0 = blockIdx.y * 128;
  const int n0 = blockIdx.x * 64;
  f32x4 acc[4][2] = {};
  char* astB = (char*)Ast;
  char* bstB = (char*)Bst;

  for (int kb = 0; kb < K; kb += 64) {
    // stage A: 128 rows x 128B = 1024 chunks of 16B, swizzled (T2 / G4)
#pragma unroll
    for (int i = 0; i < 4; ++i) {
      int c = t + 256 * i;
      int row = c >> 3, slot = c & 7;
      int gm = m0 + row;
      ushort8v v = {};
      if (gm < M) v = *(const ushort8v*)(A + (size_t)gm * K + kb + slot * 8);
      int byte = row * 128 + slot * 16;
      *(ushort8v*)(astB + (byte ^ ((row & 7) << 4))) = v;
    }
    // stage B: 64 rows x 128B = 512 chunks
#pragma unroll
    for (int i = 0; i < 2; ++i) {
      int c = t + 256 * i;
      int row = c >> 3, slot = c & 7;
      ushort8v v = *(const ushort8v*)(Bt + (size_t)(n0 + row) * K + kb + slot * 8);
      int byte = row * 128 + slot * 16;
      *(ushort8v*)(bstB + (byte ^ ((row & 7) << 4))) = v;
    }
    __syncthreads();
#pragma unroll
    for (int kk = 0; kk < 2; ++kk) {
      bf16x8 a[4], b[2];
      int kbyte = lr * 16 + kk * 64;
#pragma unroll
      for (int mi = 0; mi < 4; ++mi) {
        int row = wm * 64 + mi * 16 + lc;
        int byte = row * 128 + kbyte;
        a[mi] = *(const bf16x8*)(astB + (byte ^ ((row & 7) << 4)));
      }
#pragma unroll
      for (int ni = 0; ni < 2; ++ni) {
        int row = wn * 32 + ni * 16 + lc;
        int byte = row * 128 + kbyte;
        b[ni] = *(const bf16x8*)(bstB + (byte ^ ((row & 7) << 4)));
      }
#pragma unroll
      for (int mi = 0; mi < 4; ++mi)
#pragma unroll
        for (int ni = 0; ni < 2; ++ni)
          acc[mi][ni] =
              __builtin_amdgcn_mfma_f32_16x16x32_bf16(a[mi], b[ni], acc[mi][ni], 0, 0, 0);
    }
    __syncthreads();
  }

  // epilogue: D row=(lane>>4)*4+reg, col=lane&15  [m89/m91 verified mapping]
#pragma unroll
  for (int ni = 0; ni < 2; ++ni) {
    int colx = n0 + wn * 32 + ni * 16 + lc;
    float sc = (EPI == 0) ? scale[colx] : 0.0f;
    float sh = shift[colx];
#pragma unroll
    for (int mi = 0; mi < 4; ++mi) {
      int rbase = m0 + wm * 64 + mi * 16 + lr * 4;
#pragma unroll
      for (int r = 0; r < 4; ++r) {
        int row = rbase + r;
        if (row < M) {
          float v = acc[mi][ni][r];
          if (EPI == 0) v = fmaxf(fmaf(v, sc, sh), 0.0f);
          else v += sh;
          C[(size_t)row * N + colx] = f2b(v);
        }
      }
    }
  }
}

// ---------------- pooling: one block per graph, no atomics ----------------
__global__ __launch_bounds__(384) void k_pool(const unsigned short* __restrict__ h3,
                                              const int* __restrict__ gstart,
                                              const int* __restrict__ gend, int NF,
                                              float* __restrict__ out) {
  int g = blockIdx.x;
  int t = threadIdx.x;  // 0..383, one column each
  int s = gstart[g], e = gend[g];
  if (s >= 0 && e > s) {
    float sum = 0.0f, mx = -3.4e38f;
    for (int r = s; r < e; ++r) {
      float v = b2f(h3[(size_t)r * NF + t]);
      sum += v;
      mx = fmaxf(mx, v);
    }
    out[(size_t)g * NF + t] = sum / (float)(e - s) + mx;
  } else {
    out[(size_t)g * NF + t] = -INFINITY;  // empty graph (unreachable for this input)
  }
}

// ---------------- host launch ----------------
extern "C" void kernel_launch(void* const* d_in, const int* in_sizes, int n_in, void* d_out,
                              int out_size, void* d_ws, size_t ws_size, hipStream_t stream) {
  const float* x    = (const float*)d_in[0];
  const int* edge   = (const int*)d_in[1];
  const int* batch  = (const int*)d_in[2];
  const float* W1   = (const float*)d_in[3];
  const float* b1   = (const float*)d_in[4];
  const float* g1   = (const float*)d_in[5];
  const float* be1  = (const float*)d_in[6];
  const float* rm1  = (const float*)d_in[7];
  const float* rv1  = (const float*)d_in[8];
  const float* W2   = (const float*)d_in[9];
  const float* b2   = (const float*)d_in[10];
  const float* g2   = (const float*)d_in[11];
  const float* be2  = (const float*)d_in[12];
  const float* rm2  = (const float*)d_in[13];
  const float* rv2  = (const float*)d_in[14];
  const float* W3   = (const float*)d_in[15];
  const float* b3   = (const float*)d_in[16];

  const int NN = in_sizes[2];       // 100000
  const int E  = in_sizes[1] / 2;   // 1600000
  const int F1 = in_sizes[4];       // 256
  const int F3 = in_sizes[16];      // 384
  const int NG = out_size / F3;     // 2048
  const int K1p = 128;              // padded K for layer 1 (74 -> 128)
  const int* srcv = edge;
  const int* dstv = edge + E;

  char* p = (char*)d_ws;
  auto carve = [&](size_t bytes) -> char* {
    char* r = p;
    p += (bytes + 255) & ~(size_t)255;
    return r;
  };
  float* dinv           = (float*)carve((size_t)NN * 4);
  int* cnt              = (int*)carve((size_t)NN * 4);
  int* rowptr           = (int*)carve((size_t)(NN + 1) * 4);
  int* cursor           = (int*)carve((size_t)NN * 4);
  int* bsum             = (int*)carve(4096);
  int* col              = (int*)carve((size_t)E * 4);
  float* wt             = (float*)carve((size_t)E * 4);
  float* scale1         = (float*)carve((size_t)F1 * 4);
  float* shift1         = (float*)carve((size_t)F1 * 4);
  float* scale2         = (float*)carve((size_t)F1 * 4);
  float* shift2         = (float*)carve((size_t)F1 * 4);
  unsigned short* W1t   = (unsigned short*)carve((size_t)F1 * K1p * 2);
  unsigned short* W2t   = (unsigned short*)carve((size_t)F1 * F1 * 2);
  unsigned short* W3t   = (unsigned short*)carve((size_t)F3 * F1 * 2);
  int* gstart           = (int*)carve((size_t)NG * 4);
  int* gend             = (int*)carve((size_t)NG * 4);
  unsigned short* agg   = (unsigned short*)carve((size_t)NN * F1 * 2);
  unsigned short* h     = (unsigned short*)carve((size_t)NN * F1 * 2);
  unsigned short* h3    = (unsigned short*)carve((size_t)NN * F3 * 2);
  (void)ws_size; (void)n_in;

  // init
  hipMemsetAsync(cnt, 0, (size_t)NN * 4, stream);
  hipMemsetAsync(cursor, 0, (size_t)NN * 4, stream);
  hipMemsetAsync(gstart, 0xFF, (size_t)NG * 4, stream);
  hipMemsetAsync(gend, 0, (size_t)NG * 4, stream);
  k_bnprep<<<1, 256, 0, stream>>>(g1, be1, rm1, rv1, b1, F1, scale1, shift1);
  k_bnprep<<<1, 256, 0, stream>>>(g2, be2, rm2, rv2, b2, F1, scale2, shift2);
  k_wt<<<(F1 * K1p + 255) / 256, 256, 0, stream>>>(W1, 74, F1, K1p, W1t);
  k_wt<<<(F1 * F1 + 255) / 256, 256, 0, stream>>>(W2, F1, F1, F1, W2t);
  k_wt<<<(F3 * F1 + 255) / 256, 256, 0, stream>>>(W3, F1, F3, F1, W3t);
  k_gbounds<<<(NN + 255) / 256, 256, 0, stream>>>(batch, NN, gstart, gend);

  // CSR build
  k_edge_count<<<(E + 255) / 256, 256, 0, stream>>>(dstv, E, cnt);
  k_dinv<<<(NN + 255) / 256, 256, 0, stream>>>(cnt, NN, dinv);
  int nchunks = (NN + SCAN_CHUNK - 1) / SCAN_CHUNK;
  k_chunk_sum<<<nchunks, 256, 0, stream>>>(cnt, NN, bsum);
  k_scan_bsum<<<1, 64, 0, stream>>>(bsum, nchunks);
  k_write_rowptr<<<nchunks, 256, 0, stream>>>(cnt, NN, bsum, rowptr, E);
  k_fill<<<(E + 255) / 256, 256, 0, stream>>>(srcv, dstv, E, rowptr, cursor, dinv, col, wt);

  dim3 blk(256);
  int aggBlocks = (NN + 3) / 4;
  int gy = (NN + 127) / 128;

  // Layer 1: agg(x) -> bf16 [NN][128]; GEMM(128->256) + bn1 + relu -> h
  k_aggregate74<<<aggBlocks, blk, 0, stream>>>(x, rowptr, col, wt, dinv, NN, agg);
  {
    dim3 grid(F1 / 64, gy);
    k_gemm_mfma<0><<<grid, blk, 0, stream>>>(agg, W1t, NN, F1, K1p, scale1, shift1, h);
  }
  // Layer 2
  k_aggregate256<<<aggBlocks, blk, 0, stream>>>(h, rowptr, col, wt, dinv, NN, agg);
  {
    dim3 grid(F1 / 64, gy);
    k_gemm_mfma<0><<<grid, blk, 0, stream>>>(agg, W2t, NN, F1, F1, scale2, shift2, h);
  }
  // Layer 3: agg -> GEMM(256->384) + bias -> h3; then per-graph pool (no atomics)
  k_aggregate256<<<aggBlocks, blk, 0, stream>>>(h, rowptr, col, wt, dinv, NN, agg);
  {
    dim3 grid(F3 / 64, gy);
    k_gemm_mfma<1><<<grid, blk, 0, stream>>>(agg, W3t, NN, F3, F1, nullptr, b3, h3);
  }
  k_pool<<<NG, 384, 0, stream>>>(h3, gstart, gend, F3, (float*)d_out);
}

// Round 6
// 842.750 us; speedup vs baseline: 3.2552x; 1.2073x over previous
//
#include <hip/hip_runtime.h>

// ---------------- types & helpers ----------------
typedef __bf16 bf16x8 __attribute__((ext_vector_type(8)));
typedef float f32x4 __attribute__((ext_vector_type(4)));
typedef unsigned short ushort4v __attribute__((ext_vector_type(4)));
typedef unsigned short ushort8v __attribute__((ext_vector_type(8)));

__device__ __forceinline__ unsigned short f2b(float f) {
  unsigned u = __float_as_uint(f);
  unsigned r = u + 0x7FFFu + ((u >> 16) & 1u);
  return (unsigned short)(r >> 16);
}
__device__ __forceinline__ float b2f(unsigned short v) {
  return __uint_as_float(((unsigned)v) << 16);
}

static constexpr int SCAN_CHUNK = 1024;

// ---------------- small prep kernels ----------------
__global__ void k_bnprep(const float* __restrict__ g, const float* __restrict__ beta,
                         const float* __restrict__ rm, const float* __restrict__ rv,
                         const float* __restrict__ b, int n,
                         float* __restrict__ scale, float* __restrict__ shift) {
  int i = blockIdx.x * blockDim.x + threadIdx.x;
  if (i < n) {
    float s = g[i] * rsqrtf(rv[i] + 1e-5f);
    scale[i] = s;
    shift[i] = (b[i] - rm[i]) * s + beta[i];
  }
}

__global__ void k_edge_count(const int* __restrict__ dst, int E, int* __restrict__ cnt) {
  int i = blockIdx.x * blockDim.x + threadIdx.x;
  if (i < E) atomicAdd(&cnt[dst[i]], 1);
}

__global__ void k_dinv(const int* __restrict__ cnt, int n, float* __restrict__ dinv) {
  int i = blockIdx.x * blockDim.x + threadIdx.x;
  if (i < n) dinv[i] = rsqrtf(1.0f + (float)cnt[i]);
}

// W [K][N] f32 -> Wt [N][Kp] bf16 (zero-padded K..Kp)
__global__ void k_wt(const float* __restrict__ W, int K, int N, int Kp,
                     unsigned short* __restrict__ Wt) {
  int idx = blockIdx.x * blockDim.x + threadIdx.x;
  if (idx >= N * Kp) return;
  int n = idx / Kp, k = idx - n * Kp;
  Wt[idx] = f2b(k < K ? W[(size_t)k * N + n] : 0.0f);
}

// x f32 [n][74] -> xb bf16 [n][80] (zero pad 74..79); ushort4 per thread
__global__ void k_x2b(const float* __restrict__ x, int n, unsigned short* __restrict__ xb) {
  int idx = blockIdx.x * blockDim.x + threadIdx.x;
  if (idx >= n * 20) return;
  int row = idx / 20, j = idx - row * 20;
  int f0 = j * 4;
  ushort4v o;
#pragma unroll
  for (int j2 = 0; j2 < 4; ++j2) {
    int f = f0 + j2;
    o[j2] = (f < 74) ? f2b(x[(size_t)row * 74 + f]) : (unsigned short)0;
  }
  *(ushort4v*)(xb + (size_t)row * 80 + f0) = o;
}

// graph boundaries (batch sorted)
__global__ void k_gbounds(const int* __restrict__ batch, int n, int* __restrict__ gstart,
                          int* __restrict__ gend) {
  int i = blockIdx.x * blockDim.x + threadIdx.x;
  if (i >= n) return;
  int g = batch[i];
  if (i == 0 || batch[i - 1] != g) gstart[g] = i;
  if (i == n - 1 || batch[i + 1] != g) gend[g] = i + 1;
}

// ---------------- exclusive scan (3 kernels) ----------------
__global__ void k_chunk_sum(const int* __restrict__ cnt, int n, int* __restrict__ bsum) {
  __shared__ int s[256];
  int base = blockIdx.x * SCAN_CHUNK;
  int t = threadIdx.x;
  int v = 0;
  for (int i = t; i < SCAN_CHUNK; i += 256) {
    int idx = base + i;
    v += (idx < n) ? cnt[idx] : 0;
  }
  s[t] = v;
  __syncthreads();
  for (int o = 128; o > 0; o >>= 1) {
    if (t < o) s[t] += s[t + o];
    __syncthreads();
  }
  if (t == 0) bsum[blockIdx.x] = s[0];
}

__global__ void k_scan_bsum(int* __restrict__ bsum, int nb) {
  if (threadIdx.x == 0 && blockIdx.x == 0) {
    int acc = 0;
    for (int i = 0; i < nb; ++i) { int v = bsum[i]; bsum[i] = acc; acc += v; }
  }
}

__global__ void k_write_rowptr(const int* __restrict__ cnt, int n, const int* __restrict__ bsum,
                               int* __restrict__ rowptr, int E) {
  __shared__ int s[256];
  __shared__ int sx[257];
  int base = blockIdx.x * SCAN_CHUNK;
  int t = threadIdx.x;
  int loc[4];
  int sum = 0;
#pragma unroll
  for (int j = 0; j < 4; ++j) {
    int idx = base + t * 4 + j;
    int c = (idx < n) ? cnt[idx] : 0;
    loc[j] = sum;
    sum += c;
  }
  s[t] = sum;
  __syncthreads();
  if (t == 0) {
    int acc = 0;
    for (int i = 0; i < 256; ++i) { sx[i] = acc; acc += s[i]; }
  }
  __syncthreads();
  int off = bsum[blockIdx.x] + sx[t];
#pragma unroll
  for (int j = 0; j < 4; ++j) {
    int idx = base + t * 4 + j;
    if (idx < n) rowptr[idx] = off + loc[j];
  }
  if (blockIdx.x == 0 && t == 0) rowptr[n] = E;
}

__global__ void k_fill(const int* __restrict__ src, const int* __restrict__ dst, int E,
                       const int* __restrict__ rowptr, int* __restrict__ cursor,
                       const float* __restrict__ dinv, int* __restrict__ col,
                       float* __restrict__ wt) {
  int e = blockIdx.x * blockDim.x + threadIdx.x;
  if (e < E) {
    int d = dst[e], s = src[e];
    int p = atomicAdd(&cursor[d], 1);
    int idx = rowptr[d] + p;
    col[idx] = s;
    wt[idx] = dinv[s] * dinv[d];
  }
}

// ---------------- aggregation ----------------
// layer 1: xb bf16 [n][80] -> agg bf16 [n][128].
// One wave per node; each HALF-wave (lanes 0-19 of it) gathers one edge's 80
// features as ushort4; 2 edges per half per iter -> 4 gathers in flight.
__global__ __launch_bounds__(256) void k_aggregate74b(const unsigned short* __restrict__ xb,
                                                      const int* __restrict__ rowptr,
                                                      const int* __restrict__ col,
                                                      const float* __restrict__ wt,
                                                      const float* __restrict__ dinv, int n,
                                                      unsigned short* __restrict__ out) {
  int wid = (int)((blockIdx.x * (size_t)blockDim.x + threadIdx.x) >> 6);
  int lane = threadIdx.x & 63;
  if (wid >= n) return;
  int half = lane >> 5, hl = lane & 31;
  bool act = hl < 20;
  float acc[4] = {0.0f, 0.0f, 0.0f, 0.0f};
  int e0 = rowptr[wid], e1 = rowptr[wid + 1];
  int e = e0;
  for (; e + 3 < e1; e += 4) {
    int me0 = e + half * 2, me1 = me0 + 1;
    int s0 = col[me0], s1 = col[me1];
    float w0 = wt[me0], w1 = wt[me1];
    ushort4v v0 = {}, v1 = {};
    if (act) {
      v0 = *(const ushort4v*)(xb + (size_t)s0 * 80 + hl * 4);
      v1 = *(const ushort4v*)(xb + (size_t)s1 * 80 + hl * 4);
    }
#pragma unroll
    for (int j = 0; j < 4; ++j)
      acc[j] += w0 * b2f(v0[j]) + w1 * b2f(v1[j]);
  }
  for (int t = e + half; t < e1; t += 2) {
    int s = col[t];
    float w = wt[t];
    ushort4v v = {};
    if (act) v = *(const ushort4v*)(xb + (size_t)s * 80 + hl * 4);
#pragma unroll
    for (int j = 0; j < 4; ++j) acc[j] += w * b2f(v[j]);
  }
  // combine the two halves (all 64 lanes participate)
#pragma unroll
  for (int j = 0; j < 4; ++j) acc[j] += __shfl_xor(acc[j], 32);
  if (half == 0) {
    float di = dinv[wid];
    float sw = di * di;
    if (act) {
      ushort4v sv = *(const ushort4v*)(xb + (size_t)wid * 80 + hl * 4);
      ushort4v o;
#pragma unroll
      for (int j = 0; j < 4; ++j) o[j] = f2b(acc[j] + sw * b2f(sv[j]));
      *(ushort4v*)(out + (size_t)wid * 128 + hl * 4) = o;
    } else {
      ushort4v z = {};
      *(ushort4v*)(out + (size_t)wid * 128 + 80 + (hl - 20) * 4) = z;  // zero 80..127
    }
  }
}

// F=256 bf16 in/out, ushort4 per lane, edge loop unrolled x4 for MLP
__global__ __launch_bounds__(256) void k_aggregate256(const unsigned short* __restrict__ in,
                                                      const int* __restrict__ rowptr,
                                                      const int* __restrict__ col,
                                                      const float* __restrict__ wt,
                                                      const float* __restrict__ dinv, int n,
                                                      unsigned short* __restrict__ out) {
  int wid = (int)((blockIdx.x * (size_t)blockDim.x + threadIdx.x) >> 6);
  int lane = threadIdx.x & 63;
  if (wid >= n) return;
  float di = dinv[wid];
  float sw = di * di;
  ushort4v sv = *(const ushort4v*)(in + (size_t)wid * 256 + lane * 4);
  float acc[4];
#pragma unroll
  for (int j = 0; j < 4; ++j) acc[j] = sw * b2f(sv[j]);
  int e0 = rowptr[wid], e1 = rowptr[wid + 1];
  int e = e0;
  for (; e + 3 < e1; e += 4) {
    int s0 = col[e], s1 = col[e + 1], s2 = col[e + 2], s3 = col[e + 3];
    float w0 = wt[e], w1 = wt[e + 1], w2 = wt[e + 2], w3 = wt[e + 3];
    ushort4v v0 = *(const ushort4v*)(in + (size_t)s0 * 256 + lane * 4);
    ushort4v v1 = *(const ushort4v*)(in + (size_t)s1 * 256 + lane * 4);
    ushort4v v2 = *(const ushort4v*)(in + (size_t)s2 * 256 + lane * 4);
    ushort4v v3 = *(const ushort4v*)(in + (size_t)s3 * 256 + lane * 4);
#pragma unroll
    for (int j = 0; j < 4; ++j)
      acc[j] += w0 * b2f(v0[j]) + w1 * b2f(v1[j]) + w2 * b2f(v2[j]) + w3 * b2f(v3[j]);
  }
  for (; e < e1; ++e) {
    int s = col[e];
    float w = wt[e];
    ushort4v v = *(const ushort4v*)(in + (size_t)s * 256 + lane * 4);
#pragma unroll
    for (int j = 0; j < 4; ++j) acc[j] += w * b2f(v[j]);
  }
  ushort4v o;
#pragma unroll
  for (int j = 0; j < 4; ++j) o[j] = f2b(acc[j]);
  *(ushort4v*)(out + (size_t)wid * 256 + lane * 4) = o;
}

// ---------------- bf16 MFMA GEMM ----------------
// A [M][K] bf16, Bt [N][K] bf16 (pre-transposed weights). K % 64 == 0.
// 128x64 tile, 4 waves in 2x2 (wave tile 64x32), mfma 16x16x32.
// EPI 0: relu(v*scale+shift) -> C bf16 ; EPI 1: v + shift -> C bf16
template <int EPI>
__global__ __launch_bounds__(256) void k_gemm_mfma(const unsigned short* __restrict__ A,
                                                   const unsigned short* __restrict__ Bt,
                                                   int M, int N, int K,
                                                   const float* __restrict__ scale,
                                                   const float* __restrict__ shift,
                                                   unsigned short* __restrict__ C) {
  __shared__ __align__(16) unsigned short Ast[128 * 64];
  __shared__ __align__(16) unsigned short Bst[64 * 64];
  const int t = threadIdx.x;
  const int lane = t & 63;
  const int wid = t >> 6;
  const int wm = wid >> 1, wn = wid & 1;
  const int lr = lane >> 4, lc = lane & 15;
  const int m0 = blockIdx.y * 128;
  const int n0 = blockIdx.x * 64;
  f32x4 acc[4][2] = {};
  char* astB = (char*)Ast;
  char* bstB = (char*)Bst;

  for (int kb = 0; kb < K; kb += 64) {
    // stage A: 128 rows x 128B = 1024 chunks of 16B, swizzled (T2 / G4)
#pragma unroll
    for (int i = 0; i < 4; ++i) {
      int c = t + 256 * i;
      int row = c >> 3, slot = c & 7;
      int gm = m0 + row;
      ushort8v v = {};
      if (gm < M) v = *(const ushort8v*)(A + (size_t)gm * K + kb + slot * 8);
      int byte = row * 128 + slot * 16;
      *(ushort8v*)(astB + (byte ^ ((row & 7) << 4))) = v;
    }
    // stage B: 64 rows x 128B = 512 chunks
#pragma unroll
    for (int i = 0; i < 2; ++i) {
      int c = t + 256 * i;
      int row = c >> 3, slot = c & 7;
      ushort8v v = *(const ushort8v*)(Bt + (size_t)(n0 + row) * K + kb + slot * 8);
      int byte = row * 128 + slot * 16;
      *(ushort8v*)(bstB + (byte ^ ((row & 7) << 4))) = v;
    }
    __syncthreads();
#pragma unroll
    for (int kk = 0; kk < 2; ++kk) {
      bf16x8 a[4], b[2];
      int kbyte = lr * 16 + kk * 64;
#pragma unroll
      for (int mi = 0; mi < 4; ++mi) {
        int row = wm * 64 + mi * 16 + lc;
        int byte = row * 128 + kbyte;
        a[mi] = *(const bf16x8*)(astB + (byte ^ ((row & 7) << 4)));
      }
#pragma unroll
      for (int ni = 0; ni < 2; ++ni) {
        int row = wn * 32 + ni * 16 + lc;
        int byte = row * 128 + kbyte;
        b[ni] = *(const bf16x8*)(bstB + (byte ^ ((row & 7) << 4)));
      }
#pragma unroll
      for (int mi = 0; mi < 4; ++mi)
#pragma unroll
        for (int ni = 0; ni < 2; ++ni)
          acc[mi][ni] =
              __builtin_amdgcn_mfma_f32_16x16x32_bf16(a[mi], b[ni], acc[mi][ni], 0, 0, 0);
    }
    __syncthreads();
  }

  // epilogue: D row=(lane>>4)*4+reg, col=lane&15  [m89/m91 verified mapping]
#pragma unroll
  for (int ni = 0; ni < 2; ++ni) {
    int colx = n0 + wn * 32 + ni * 16 + lc;
    float sc = (EPI == 0) ? scale[colx] : 0.0f;
    float sh = shift[colx];
#pragma unroll
    for (int mi = 0; mi < 4; ++mi) {
      int rbase = m0 + wm * 64 + mi * 16 + lr * 4;
#pragma unroll
      for (int r = 0; r < 4; ++r) {
        int row = rbase + r;
        if (row < M) {
          float v = acc[mi][ni][r];
          if (EPI == 0) v = fmaxf(fmaf(v, sc, sh), 0.0f);
          else v += sh;
          C[(size_t)row * N + colx] = f2b(v);
        }
      }
    }
  }
}

// ---------------- pooling: one block per graph, no atomics ----------------
__global__ __launch_bounds__(384) void k_pool(const unsigned short* __restrict__ h3,
                                              const int* __restrict__ gstart,
                                              const int* __restrict__ gend, int NF,
                                              float* __restrict__ out) {
  int g = blockIdx.x;
  int t = threadIdx.x;  // 0..383, one column each
  int s = gstart[g], e = gend[g];
  if (s >= 0 && e > s) {
    float sum = 0.0f, mx = -3.4e38f;
    for (int r = s; r < e; ++r) {
      float v = b2f(h3[(size_t)r * NF + t]);
      sum += v;
      mx = fmaxf(mx, v);
    }
    out[(size_t)g * NF + t] = sum / (float)(e - s) + mx;
  } else {
    out[(size_t)g * NF + t] = -INFINITY;  // empty graph (unreachable for this input)
  }
}

// ---------------- host launch ----------------
extern "C" void kernel_launch(void* const* d_in, const int* in_sizes, int n_in, void* d_out,
                              int out_size, void* d_ws, size_t ws_size, hipStream_t stream) {
  const float* x    = (const float*)d_in[0];
  const int* edge   = (const int*)d_in[1];
  const int* batch  = (const int*)d_in[2];
  const float* W1   = (const float*)d_in[3];
  const float* b1   = (const float*)d_in[4];
  const float* g1   = (const float*)d_in[5];
  const float* be1  = (const float*)d_in[6];
  const float* rm1  = (const float*)d_in[7];
  const float* rv1  = (const float*)d_in[8];
  const float* W2   = (const float*)d_in[9];
  const float* b2   = (const float*)d_in[10];
  const float* g2   = (const float*)d_in[11];
  const float* be2  = (const float*)d_in[12];
  const float* rm2  = (const float*)d_in[13];
  const float* rv2  = (const float*)d_in[14];
  const float* W3   = (const float*)d_in[15];
  const float* b3   = (const float*)d_in[16];

  const int NN = in_sizes[2];       // 100000
  const int E  = in_sizes[1] / 2;   // 1600000
  const int F1 = in_sizes[4];       // 256
  const int F3 = in_sizes[16];      // 384
  const int NG = out_size / F3;     // 2048
  const int K1p = 128;              // padded K for layer 1 (74 -> 128)
  const int* srcv = edge;
  const int* dstv = edge + E;

  char* p = (char*)d_ws;
  auto carve = [&](size_t bytes) -> char* {
    char* r = p;
    p += (bytes + 255) & ~(size_t)255;
    return r;
  };
  float* dinv           = (float*)carve((size_t)NN * 4);
  int* cnt              = (int*)carve((size_t)NN * 4);
  int* rowptr           = (int*)carve((size_t)(NN + 1) * 4);
  int* cursor           = (int*)carve((size_t)NN * 4);
  int* bsum             = (int*)carve(4096);
  int* col              = (int*)carve((size_t)E * 4);
  float* wt             = (float*)carve((size_t)E * 4);
  float* scale1         = (float*)carve((size_t)F1 * 4);
  float* shift1         = (float*)carve((size_t)F1 * 4);
  float* scale2         = (float*)carve((size_t)F1 * 4);
  float* shift2         = (float*)carve((size_t)F1 * 4);
  unsigned short* W1t   = (unsigned short*)carve((size_t)F1 * K1p * 2);
  unsigned short* W2t   = (unsigned short*)carve((size_t)F1 * F1 * 2);
  unsigned short* W3t   = (unsigned short*)carve((size_t)F3 * F1 * 2);
  int* gstart           = (int*)carve((size_t)NG * 4);
  int* gend             = (int*)carve((size_t)NG * 4);
  unsigned short* xb    = (unsigned short*)carve((size_t)NN * 80 * 2);
  unsigned short* agg   = (unsigned short*)carve((size_t)NN * F1 * 2);
  unsigned short* h     = (unsigned short*)carve((size_t)NN * F1 * 2);
  unsigned short* h3    = (unsigned short*)carve((size_t)NN * F3 * 2);
  (void)ws_size; (void)n_in;

  // init
  hipMemsetAsync(cnt, 0, (size_t)NN * 4, stream);
  hipMemsetAsync(cursor, 0, (size_t)NN * 4, stream);
  hipMemsetAsync(gstart, 0xFF, (size_t)NG * 4, stream);
  hipMemsetAsync(gend, 0, (size_t)NG * 4, stream);
  k_bnprep<<<1, 256, 0, stream>>>(g1, be1, rm1, rv1, b1, F1, scale1, shift1);
  k_bnprep<<<1, 256, 0, stream>>>(g2, be2, rm2, rv2, b2, F1, scale2, shift2);
  k_wt<<<(F1 * K1p + 255) / 256, 256, 0, stream>>>(W1, 74, F1, K1p, W1t);
  k_wt<<<(F1 * F1 + 255) / 256, 256, 0, stream>>>(W2, F1, F1, F1, W2t);
  k_wt<<<(F3 * F1 + 255) / 256, 256, 0, stream>>>(W3, F1, F3, F1, W3t);
  k_x2b<<<(NN * 20 + 255) / 256, 256, 0, stream>>>(x, NN, xb);
  k_gbounds<<<(NN + 255) / 256, 256, 0, stream>>>(batch, NN, gstart, gend);

  // CSR build
  k_edge_count<<<(E + 255) / 256, 256, 0, stream>>>(dstv, E, cnt);
  k_dinv<<<(NN + 255) / 256, 256, 0, stream>>>(cnt, NN, dinv);
  int nchunks = (NN + SCAN_CHUNK - 1) / SCAN_CHUNK;
  k_chunk_sum<<<nchunks, 256, 0, stream>>>(cnt, NN, bsum);
  k_scan_bsum<<<1, 64, 0, stream>>>(bsum, nchunks);
  k_write_rowptr<<<nchunks, 256, 0, stream>>>(cnt, NN, bsum, rowptr, E);
  k_fill<<<(E + 255) / 256, 256, 0, stream>>>(srcv, dstv, E, rowptr, cursor, dinv, col, wt);

  dim3 blk(256);
  int aggBlocks = (NN + 3) / 4;
  int gy = (NN + 127) / 128;

  // Layer 1: agg(xb) -> bf16 [NN][128]; GEMM(128->256) + bn1 + relu -> h
  k_aggregate74b<<<aggBlocks, blk, 0, stream>>>(xb, rowptr, col, wt, dinv, NN, agg);
  {
    dim3 grid(F1 / 64, gy);
    k_gemm_mfma<0><<<grid, blk, 0, stream>>>(agg, W1t, NN, F1, K1p, scale1, shift1, h);
  }
  // Layer 2
  k_aggregate256<<<aggBlocks, blk, 0, stream>>>(h, rowptr, col, wt, dinv, NN, agg);
  {
    dim3 grid(F1 / 64, gy);
    k_gemm_mfma<0><<<grid, blk, 0, stream>>>(agg, W2t, NN, F1, F1, scale2, shift2, h);
  }
  // Layer 3: agg -> GEMM(256->384) + bias -> h3; then per-graph pool (no atomics)
  k_aggregate256<<<aggBlocks, blk, 0, stream>>>(h, rowptr, col, wt, dinv, NN, agg);
  {
    dim3 grid(F3 / 64, gy);
    k_gemm_mfma<1><<<grid, blk, 0, stream>>>(agg, W3t, NN, F3, F1, nullptr, b3, h3);
  }
  k_pool<<<NG, 384, 0, stream>>>(h3, gstart, gend, F3, (float*)d_out);
}

// Round 7
// 802.271 us; speedup vs baseline: 3.4194x; 1.0505x over previous
//
#include <hip/hip_runtime.h>

// ---------------- types & helpers ----------------
typedef __bf16 bf16x8 __attribute__((ext_vector_type(8)));
typedef float f32x4 __attribute__((ext_vector_type(4)));
typedef unsigned short ushort4v __attribute__((ext_vector_type(4)));
typedef unsigned short ushort8v __attribute__((ext_vector_type(8)));

__device__ __forceinline__ unsigned short f2b(float f) {
  unsigned u = __float_as_uint(f);
  unsigned r = u + 0x7FFFu + ((u >> 16) & 1u);
  return (unsigned short)(r >> 16);
}
__device__ __forceinline__ float b2f(unsigned short v) {
  return __uint_as_float(((unsigned)v) << 16);
}

static constexpr int SCAN_CHUNK = 1024;

// ---------------- small prep kernels ----------------
__global__ void k_bnprep(const float* __restrict__ g, const float* __restrict__ beta,
                         const float* __restrict__ rm, const float* __restrict__ rv,
                         const float* __restrict__ b, int n,
                         float* __restrict__ scale, float* __restrict__ shift) {
  int i = blockIdx.x * blockDim.x + threadIdx.x;
  if (i < n) {
    float s = g[i] * rsqrtf(rv[i] + 1e-5f);
    scale[i] = s;
    shift[i] = (b[i] - rm[i]) * s + beta[i];
  }
}

__global__ void k_edge_count(const int* __restrict__ dst, int E, int* __restrict__ cnt) {
  int i = blockIdx.x * blockDim.x + threadIdx.x;
  if (i < E) atomicAdd(&cnt[dst[i]], 1);
}

__global__ void k_dinv(const int* __restrict__ cnt, int n, float* __restrict__ dinv) {
  int i = blockIdx.x * blockDim.x + threadIdx.x;
  if (i < n) dinv[i] = rsqrtf(1.0f + (float)cnt[i]);
}

// W [K][N] f32 -> Wt [N][Kp] bf16 (zero-padded K..Kp)
__global__ void k_wt(const float* __restrict__ W, int K, int N, int Kp,
                     unsigned short* __restrict__ Wt) {
  int idx = blockIdx.x * blockDim.x + threadIdx.x;
  if (idx >= N * Kp) return;
  int n = idx / Kp, k = idx - n * Kp;
  Wt[idx] = f2b(k < K ? W[(size_t)k * N + n] : 0.0f);
}

// x f32 [n][74] -> xb bf16 [n][80] (zero pad 74..79); ushort4 per thread
__global__ void k_x2b(const float* __restrict__ x, int n, unsigned short* __restrict__ xb) {
  int idx = blockIdx.x * blockDim.x + threadIdx.x;
  if (idx >= n * 20) return;
  int row = idx / 20, j = idx - row * 20;
  int f0 = j * 4;
  ushort4v o;
#pragma unroll
  for (int j2 = 0; j2 < 4; ++j2) {
    int f = f0 + j2;
    o[j2] = (f < 74) ? f2b(x[(size_t)row * 74 + f]) : (unsigned short)0;
  }
  *(ushort4v*)(xb + (size_t)row * 80 + f0) = o;
}

// graph boundaries (batch sorted)
__global__ void k_gbounds(const int* __restrict__ batch, int n, int* __restrict__ gstart,
                          int* __restrict__ gend) {
  int i = blockIdx.x * blockDim.x + threadIdx.x;
  if (i >= n) return;
  int g = batch[i];
  if (i == 0 || batch[i - 1] != g) gstart[g] = i;
  if (i == n - 1 || batch[i + 1] != g) gend[g] = i + 1;
}

// ---------------- exclusive scan (3 kernels) ----------------
__global__ void k_chunk_sum(const int* __restrict__ cnt, int n, int* __restrict__ bsum) {
  __shared__ int s[256];
  int base = blockIdx.x * SCAN_CHUNK;
  int t = threadIdx.x;
  int v = 0;
  for (int i = t; i < SCAN_CHUNK; i += 256) {
    int idx = base + i;
    v += (idx < n) ? cnt[idx] : 0;
  }
  s[t] = v;
  __syncthreads();
  for (int o = 128; o > 0; o >>= 1) {
    if (t < o) s[t] += s[t + o];
    __syncthreads();
  }
  if (t == 0) bsum[blockIdx.x] = s[0];
}

__global__ void k_scan_bsum(int* __restrict__ bsum, int nb) {
  if (threadIdx.x == 0 && blockIdx.x == 0) {
    int acc = 0;
    for (int i = 0; i < nb; ++i) { int v = bsum[i]; bsum[i] = acc; acc += v; }
  }
}

__global__ void k_write_rowptr(const int* __restrict__ cnt, int n, const int* __restrict__ bsum,
                               int* __restrict__ rowptr, int E) {
  __shared__ int s[256];
  __shared__ int sx[257];
  int base = blockIdx.x * SCAN_CHUNK;
  int t = threadIdx.x;
  int loc[4];
  int sum = 0;
#pragma unroll
  for (int j = 0; j < 4; ++j) {
    int idx = base + t * 4 + j;
    int c = (idx < n) ? cnt[idx] : 0;
    loc[j] = sum;
    sum += c;
  }
  s[t] = sum;
  __syncthreads();
  if (t == 0) {
    int acc = 0;
    for (int i = 0; i < 256; ++i) { sx[i] = acc; acc += s[i]; }
  }
  __syncthreads();
  int off = bsum[blockIdx.x] + sx[t];
#pragma unroll
  for (int j = 0; j < 4; ++j) {
    int idx = base + t * 4 + j;
    if (idx < n) rowptr[idx] = off + loc[j];
  }
  if (blockIdx.x == 0 && t == 0) rowptr[n] = E;
}

// packed CSR payload: cw[idx] = {src, bits(weight)} -> ONE 8B scatter per edge
__global__ void k_fill(const int* __restrict__ src, const int* __restrict__ dst, int E,
                       const int* __restrict__ rowptr, int* __restrict__ cursor,
                       const float* __restrict__ dinv, uint2* __restrict__ cw) {
  int e = blockIdx.x * blockDim.x + threadIdx.x;
  if (e < E) {
    int d = dst[e], s = src[e];
    int p = atomicAdd(&cursor[d], 1);
    int idx = rowptr[d] + p;
    uint2 v;
    v.x = (unsigned)s;
    v.y = __float_as_uint(dinv[s] * dinv[d]);
    cw[idx] = v;
  }
}

// ---------------- aggregation ----------------
// layer 1: xb bf16 [n][80] -> agg bf16 [n][128].
// One wave per node; each HALF-wave (lanes 0-19 of it) gathers one edge's 80
// features as ushort4; 4 edges per half per iter -> 8 gathers in flight.
__global__ __launch_bounds__(256) void k_aggregate74b(const unsigned short* __restrict__ xb,
                                                      const int* __restrict__ rowptr,
                                                      const uint2* __restrict__ cw,
                                                      const float* __restrict__ dinv, int n,
                                                      unsigned short* __restrict__ out) {
  int wid = (int)((blockIdx.x * (size_t)blockDim.x + threadIdx.x) >> 6);
  int lane = threadIdx.x & 63;
  if (wid >= n) return;
  int half = lane >> 5, hl = lane & 31;
  bool act = hl < 20;
  float acc[4] = {0.0f, 0.0f, 0.0f, 0.0f};
  int e0 = rowptr[wid], e1 = rowptr[wid + 1];
  int e = e0;
  for (; e + 7 < e1; e += 8) {
    int b = e + half * 4;
    uint2 c0 = cw[b], c1 = cw[b + 1], c2 = cw[b + 2], c3 = cw[b + 3];
    ushort4v v0 = {}, v1 = {}, v2 = {}, v3 = {};
    if (act) {
      v0 = *(const ushort4v*)(xb + (size_t)c0.x * 80 + hl * 4);
      v1 = *(const ushort4v*)(xb + (size_t)c1.x * 80 + hl * 4);
      v2 = *(const ushort4v*)(xb + (size_t)c2.x * 80 + hl * 4);
      v3 = *(const ushort4v*)(xb + (size_t)c3.x * 80 + hl * 4);
    }
    float w0 = __uint_as_float(c0.y), w1 = __uint_as_float(c1.y);
    float w2 = __uint_as_float(c2.y), w3 = __uint_as_float(c3.y);
#pragma unroll
    for (int j = 0; j < 4; ++j)
      acc[j] += w0 * b2f(v0[j]) + w1 * b2f(v1[j]) + w2 * b2f(v2[j]) + w3 * b2f(v3[j]);
  }
  for (int t = e + half; t < e1; t += 2) {
    uint2 c = cw[t];
    float w = __uint_as_float(c.y);
    ushort4v v = {};
    if (act) v = *(const ushort4v*)(xb + (size_t)c.x * 80 + hl * 4);
#pragma unroll
    for (int j = 0; j < 4; ++j) acc[j] += w * b2f(v[j]);
  }
  // combine the two halves (all 64 lanes participate)
#pragma unroll
  for (int j = 0; j < 4; ++j) acc[j] += __shfl_xor(acc[j], 32);
  if (half == 0) {
    float di = dinv[wid];
    float sw = di * di;
    if (act) {
      ushort4v sv = *(const ushort4v*)(xb + (size_t)wid * 80 + hl * 4);
      ushort4v o;
#pragma unroll
      for (int j = 0; j < 4; ++j) o[j] = f2b(acc[j] + sw * b2f(sv[j]));
      *(ushort4v*)(out + (size_t)wid * 128 + hl * 4) = o;
    } else {
      ushort4v z = {};
      *(ushort4v*)(out + (size_t)wid * 128 + 80 + (hl - 20) * 4) = z;  // zero 80..127
    }
  }
}

// F=256 bf16 in/out, ushort4 per lane, edge loop unrolled x8 for MLP
__global__ __launch_bounds__(256) void k_aggregate256(const unsigned short* __restrict__ in,
                                                      const int* __restrict__ rowptr,
                                                      const uint2* __restrict__ cw,
                                                      const float* __restrict__ dinv, int n,
                                                      unsigned short* __restrict__ out) {
  int wid = (int)((blockIdx.x * (size_t)blockDim.x + threadIdx.x) >> 6);
  int lane = threadIdx.x & 63;
  if (wid >= n) return;
  float di = dinv[wid];
  float sw = di * di;
  ushort4v sv = *(const ushort4v*)(in + (size_t)wid * 256 + lane * 4);
  float acc[4];
#pragma unroll
  for (int j = 0; j < 4; ++j) acc[j] = sw * b2f(sv[j]);
  int e0 = rowptr[wid], e1 = rowptr[wid + 1];
  int e = e0;
  for (; e + 7 < e1; e += 8) {
    uint2 c[8];
    ushort4v v[8];
#pragma unroll
    for (int q = 0; q < 8; ++q) c[q] = cw[e + q];
#pragma unroll
    for (int q = 0; q < 8; ++q)
      v[q] = *(const ushort4v*)(in + (size_t)c[q].x * 256 + lane * 4);
#pragma unroll
    for (int q = 0; q < 8; ++q) {
      float w = __uint_as_float(c[q].y);
#pragma unroll
      for (int j = 0; j < 4; ++j) acc[j] += w * b2f(v[q][j]);
    }
  }
  for (; e + 3 < e1; e += 4) {
    uint2 c0 = cw[e], c1 = cw[e + 1], c2 = cw[e + 2], c3 = cw[e + 3];
    ushort4v v0 = *(const ushort4v*)(in + (size_t)c0.x * 256 + lane * 4);
    ushort4v v1 = *(const ushort4v*)(in + (size_t)c1.x * 256 + lane * 4);
    ushort4v v2 = *(const ushort4v*)(in + (size_t)c2.x * 256 + lane * 4);
    ushort4v v3 = *(const ushort4v*)(in + (size_t)c3.x * 256 + lane * 4);
    float w0 = __uint_as_float(c0.y), w1 = __uint_as_float(c1.y);
    float w2 = __uint_as_float(c2.y), w3 = __uint_as_float(c3.y);
#pragma unroll
    for (int j = 0; j < 4; ++j)
      acc[j] += w0 * b2f(v0[j]) + w1 * b2f(v1[j]) + w2 * b2f(v2[j]) + w3 * b2f(v3[j]);
  }
  for (; e < e1; ++e) {
    uint2 c = cw[e];
    float w = __uint_as_float(c.y);
    ushort4v v = *(const ushort4v*)(in + (size_t)c.x * 256 + lane * 4);
#pragma unroll
    for (int j = 0; j < 4; ++j) acc[j] += w * b2f(v[j]);
  }
  ushort4v o;
#pragma unroll
  for (int j = 0; j < 4; ++j) o[j] = f2b(acc[j]);
  *(ushort4v*)(out + (size_t)wid * 256 + lane * 4) = o;
}

// ---------------- bf16 MFMA GEMM ----------------
// A [M][K] bf16, Bt [N][K] bf16 (pre-transposed weights). K % 64 == 0.
// 128x64 tile, 4 waves in 2x2 (wave tile 64x32), mfma 16x16x32.
// EPI 0: relu(v*scale+shift) -> C bf16 ; EPI 1: v + shift -> C bf16
template <int EPI>
__global__ __launch_bounds__(256) void k_gemm_mfma(const unsigned short* __restrict__ A,
                                                   const unsigned short* __restrict__ Bt,
                                                   int M, int N, int K,
                                                   const float* __restrict__ scale,
                                                   const float* __restrict__ shift,
                                                   unsigned short* __restrict__ C) {
  __shared__ __align__(16) unsigned short Ast[128 * 64];
  __shared__ __align__(16) unsigned short Bst[64 * 64];
  const int t = threadIdx.x;
  const int lane = t & 63;
  const int wid = t >> 6;
  const int wm = wid >> 1, wn = wid & 1;
  const int lr = lane >> 4, lc = lane & 15;
  const int m0 = blockIdx.y * 128;
  const int n0 = blockIdx.x * 64;
  f32x4 acc[4][2] = {};
  char* astB = (char*)Ast;
  char* bstB = (char*)Bst;

  for (int kb = 0; kb < K; kb += 64) {
    // stage A: 128 rows x 128B = 1024 chunks of 16B, swizzled (T2 / G4)
#pragma unroll
    for (int i = 0; i < 4; ++i) {
      int c = t + 256 * i;
      int row = c >> 3, slot = c & 7;
      int gm = m0 + row;
      ushort8v v = {};
      if (gm < M) v = *(const ushort8v*)(A + (size_t)gm * K + kb + slot * 8);
      int byte = row * 128 + slot * 16;
      *(ushort8v*)(astB + (byte ^ ((row & 7) << 4))) = v;
    }
    // stage B: 64 rows x 128B = 512 chunks
#pragma unroll
    for (int i = 0; i < 2; ++i) {
      int c = t + 256 * i;
      int row = c >> 3, slot = c & 7;
      ushort8v v = *(const ushort8v*)(Bt + (size_t)(n0 + row) * K + kb + slot * 8);
      int byte = row * 128 + slot * 16;
      *(ushort8v*)(bstB + (byte ^ ((row & 7) << 4))) = v;
    }
    __syncthreads();
#pragma unroll
    for (int kk = 0; kk < 2; ++kk) {
      bf16x8 a[4], b[2];
      int kbyte = lr * 16 + kk * 64;
#pragma unroll
      for (int mi = 0; mi < 4; ++mi) {
        int row = wm * 64 + mi * 16 + lc;
        int byte = row * 128 + kbyte;
        a[mi] = *(const bf16x8*)(astB + (byte ^ ((row & 7) << 4)));
      }
#pragma unroll
      for (int ni = 0; ni < 2; ++ni) {
        int row = wn * 32 + ni * 16 + lc;
        int byte = row * 128 + kbyte;
        b[ni] = *(const bf16x8*)(bstB + (byte ^ ((row & 7) << 4)));
      }
#pragma unroll
      for (int mi = 0; mi < 4; ++mi)
#pragma unroll
        for (int ni = 0; ni < 2; ++ni)
          acc[mi][ni] =
              __builtin_amdgcn_mfma_f32_16x16x32_bf16(a[mi], b[ni], acc[mi][ni], 0, 0, 0);
    }
    __syncthreads();
  }

  // epilogue: D row=(lane>>4)*4+reg, col=lane&15  [m89/m91 verified mapping]
#pragma unroll
  for (int ni = 0; ni < 2; ++ni) {
    int colx = n0 + wn * 32 + ni * 16 + lc;
    float sc = (EPI == 0) ? scale[colx] : 0.0f;
    float sh = shift[colx];
#pragma unroll
    for (int mi = 0; mi < 4; ++mi) {
      int rbase = m0 + wm * 64 + mi * 16 + lr * 4;
#pragma unroll
      for (int r = 0; r < 4; ++r) {
        int row = rbase + r;
        if (row < M) {
          float v = acc[mi][ni][r];
          if (EPI == 0) v = fmaxf(fmaf(v, sc, sh), 0.0f);
          else v += sh;
          C[(size_t)row * N + colx] = f2b(v);
        }
      }
    }
  }
}

// ---------------- pooling: one block per graph, no atomics ----------------
__global__ __launch_bounds__(384) void k_pool(const unsigned short* __restrict__ h3,
                                              const int* __restrict__ gstart,
                                              const int* __restrict__ gend, int NF,
                                              float* __restrict__ out) {
  int g = blockIdx.x;
  int t = threadIdx.x;  // 0..383, one column each
  int s = gstart[g], e = gend[g];
  if (s >= 0 && e > s) {
    float sum = 0.0f, mx = -3.4e38f;
    for (int r = s; r < e; ++r) {
      float v = b2f(h3[(size_t)r * NF + t]);
      sum += v;
      mx = fmaxf(mx, v);
    }
    out[(size_t)g * NF + t] = sum / (float)(e - s) + mx;
  } else {
    out[(size_t)g * NF + t] = -INFINITY;  // empty graph (unreachable for this input)
  }
}

// ---------------- host launch ----------------
extern "C" void kernel_launch(void* const* d_in, const int* in_sizes, int n_in, void* d_out,
                              int out_size, void* d_ws, size_t ws_size, hipStream_t stream) {
  const float* x    = (const float*)d_in[0];
  const int* edge   = (const int*)d_in[1];
  const int* batch  = (const int*)d_in[2];
  const float* W1   = (const float*)d_in[3];
  const float* b1   = (const float*)d_in[4];
  const float* g1   = (const float*)d_in[5];
  const float* be1  = (const float*)d_in[6];
  const float* rm1  = (const float*)d_in[7];
  const float* rv1  = (const float*)d_in[8];
  const float* W2   = (const float*)d_in[9];
  const float* b2   = (const float*)d_in[10];
  const float* g2   = (const float*)d_in[11];
  const float* be2  = (const float*)d_in[12];
  const float* rm2  = (const float*)d_in[13];
  const float* rv2  = (const float*)d_in[14];
  const float* W3   = (const float*)d_in[15];
  const float* b3   = (const float*)d_in[16];

  const int NN = in_sizes[2];       // 100000
  const int E  = in_sizes[1] / 2;   // 1600000
  const int F1 = in_sizes[4];       // 256
  const int F3 = in_sizes[16];      // 384
  const int NG = out_size / F3;     // 2048
  const int K1p = 128;              // padded K for layer 1 (74 -> 128)
  const int* srcv = edge;
  const int* dstv = edge + E;

  char* p = (char*)d_ws;
  auto carve = [&](size_t bytes) -> char* {
    char* r = p;
    p += (bytes + 255) & ~(size_t)255;
    return r;
  };
  float* dinv           = (float*)carve((size_t)NN * 4);
  int* cnt              = (int*)carve((size_t)NN * 4);
  int* rowptr           = (int*)carve((size_t)(NN + 1) * 4);
  int* cursor           = (int*)carve((size_t)NN * 4);
  int* bsum             = (int*)carve(4096);
  uint2* cw             = (uint2*)carve((size_t)E * 8);
  float* scale1         = (float*)carve((size_t)F1 * 4);
  float* shift1         = (float*)carve((size_t)F1 * 4);
  float* scale2         = (float*)carve((size_t)F1 * 4);
  float* shift2         = (float*)carve((size_t)F1 * 4);
  unsigned short* W1t   = (unsigned short*)carve((size_t)F1 * K1p * 2);
  unsigned short* W2t   = (unsigned short*)carve((size_t)F1 * F1 * 2);
  unsigned short* W3t   = (unsigned short*)carve((size_t)F3 * F1 * 2);
  int* gstart           = (int*)carve((size_t)NG * 4);
  int* gend             = (int*)carve((size_t)NG * 4);
  unsigned short* xb    = (unsigned short*)carve((size_t)NN * 80 * 2);
  unsigned short* agg   = (unsigned short*)carve((size_t)NN * F1 * 2);
  unsigned short* h     = (unsigned short*)carve((size_t)NN * F1 * 2);
  unsigned short* h3    = (unsigned short*)carve((size_t)NN * F3 * 2);
  (void)ws_size; (void)n_in;

  // init
  hipMemsetAsync(cnt, 0, (size_t)NN * 4, stream);
  hipMemsetAsync(cursor, 0, (size_t)NN * 4, stream);
  hipMemsetAsync(gstart, 0xFF, (size_t)NG * 4, stream);
  hipMemsetAsync(gend, 0, (size_t)NG * 4, stream);
  k_bnprep<<<1, 256, 0, stream>>>(g1, be1, rm1, rv1, b1, F1, scale1, shift1);
  k_bnprep<<<1, 256, 0, stream>>>(g2, be2, rm2, rv2, b2, F1, scale2, shift2);
  k_wt<<<(F1 * K1p + 255) / 256, 256, 0, stream>>>(W1, 74, F1, K1p, W1t);
  k_wt<<<(F1 * F1 + 255) / 256, 256, 0, stream>>>(W2, F1, F1, F1, W2t);
  k_wt<<<(F3 * F1 + 255) / 256, 256, 0, stream>>>(W3, F1, F3, F1, W3t);
  k_x2b<<<(NN * 20 + 255) / 256, 256, 0, stream>>>(x, NN, xb);
  k_gbounds<<<(NN + 255) / 256, 256, 0, stream>>>(batch, NN, gstart, gend);

  // CSR build
  k_edge_count<<<(E + 255) / 256, 256, 0, stream>>>(dstv, E, cnt);
  k_dinv<<<(NN + 255) / 256, 256, 0, stream>>>(cnt, NN, dinv);
  int nchunks = (NN + SCAN_CHUNK - 1) / SCAN_CHUNK;
  k_chunk_sum<<<nchunks, 256, 0, stream>>>(cnt, NN, bsum);
  k_scan_bsum<<<1, 64, 0, stream>>>(bsum, nchunks);
  k_write_rowptr<<<nchunks, 256, 0, stream>>>(cnt, NN, bsum, rowptr, E);
  k_fill<<<(E + 255) / 256, 256, 0, stream>>>(srcv, dstv, E, rowptr, cursor, dinv, cw);

  dim3 blk(256);
  int aggBlocks = (NN + 3) / 4;
  int gy = (NN + 127) / 128;

  // Layer 1: agg(xb) -> bf16 [NN][128]; GEMM(128->256) + bn1 + relu -> h
  k_aggregate74b<<<aggBlocks, blk, 0, stream>>>(xb, rowptr, cw, dinv, NN, agg);
  {
    dim3 grid(F1 / 64, gy);
    k_gemm_mfma<0><<<grid, blk, 0, stream>>>(agg, W1t, NN, F1, K1p, scale1, shift1, h);
  }
  // Layer 2
  k_aggregate256<<<aggBlocks, blk, 0, stream>>>(h, rowptr, cw, dinv, NN, agg);
  {
    dim3 grid(F1 / 64, gy);
    k_gemm_mfma<0><<<grid, blk, 0, stream>>>(agg, W2t, NN, F1, F1, scale2, shift2, h);
  }
  // Layer 3: agg -> GEMM(256->384) + bias -> h3; then per-graph pool (no atomics)
  k_aggregate256<<<aggBlocks, blk, 0, stream>>>(h, rowptr, cw, dinv, NN, agg);
  {
    dim3 grid(F3 / 64, gy);
    k_gemm_mfma<1><<<grid, blk, 0, stream>>>(agg, W3t, NN, F3, F1, nullptr, b3, h3);
  }
  k_pool<<<NG, 384, 0, stream>>>(h3, gstart, gend, F3, (float*)d_out);
}

// Round 9
// 744.501 us; speedup vs baseline: 3.6847x; 1.0776x over previous
//
#include <hip/hip_runtime.h>

// ---------------- types & helpers ----------------
typedef __bf16 bf16x8 __attribute__((ext_vector_type(8)));
typedef float f32x4 __attribute__((ext_vector_type(4)));
typedef float f32x2 __attribute__((ext_vector_type(2)));
typedef unsigned short ushort4v __attribute__((ext_vector_type(4)));
typedef unsigned short ushort8v __attribute__((ext_vector_type(8)));

__device__ __forceinline__ unsigned short f2b(float f) {
  unsigned u = __float_as_uint(f);
  unsigned r = u + 0x7FFFu + ((u >> 16) & 1u);
  return (unsigned short)(r >> 16);
}
__device__ __forceinline__ float b2f(unsigned short v) {
  return __uint_as_float(((unsigned)v) << 16);
}

// ---- OCP e4m3 helpers (gfx950 HW cvt interprets fp8 as OCP) ----
__device__ __forceinline__ void fp8x4_to_f32(unsigned w, float out[4]) {
#if __has_builtin(__builtin_amdgcn_cvt_pk_f32_fp8)
  f32x2 lo = __builtin_amdgcn_cvt_pk_f32_fp8(w, false);
  f32x2 hi = __builtin_amdgcn_cvt_pk_f32_fp8(w, true);
  out[0] = lo[0]; out[1] = lo[1]; out[2] = hi[0]; out[3] = hi[1];
#else
#pragma unroll
  for (int i = 0; i < 4; ++i) {
    unsigned u = (w >> (8 * i)) & 0xffu;
    unsigned em = u & 0x7fu;
    float nrm = __uint_as_float((em + 960u) << 20);  // (e+120)<<23 | m<<20
    float sub = (float)em * 0x1p-9f;
    float mag = (em >= 8u) ? nrm : sub;
    out[i] = (u & 0x80u) ? -mag : mag;
  }
#endif
}

// software RTN encode f32 -> OCP e4m3 (cold path: GEMM epilogue only)
__device__ __forceinline__ unsigned char f32_to_fp8(float f) {
  float a = fabsf(f);
  unsigned s = (__float_as_uint(f) >> 31) << 7;
  a = fminf(a, 448.0f);
  unsigned r;
  if (a >= 0x1p-6f) {  // normal range
    unsigned b = __float_as_uint(a);
    unsigned m = b & 0x7fffffu;
    int ei = (int)(b >> 23) - 127;
    unsigned mr = (m + 0x80000u) >> 20;          // round mantissa to 3 bits (+carry)
    unsigned ee = (unsigned)(ei + 7) + (mr >> 3);
    mr &= 7u;
    if (ee >= 16u) { ee = 15u; mr = 6u; }        // clamp to 448 (0x7E), avoid NaN
    r = (ee << 3) | mr;
  } else {             // subnormal / zero: round(a*2^9); m==8 lands on first normal
    unsigned m = (unsigned)(a * 512.0f + 0.5f);
    r = m;
  }
  return (unsigned char)(s | r);
}

static constexpr int SCAN_CHUNK = 1024;

// ---------------- small prep kernels ----------------
__global__ void k_bnprep(const float* __restrict__ g, const float* __restrict__ beta,
                         const float* __restrict__ rm, const float* __restrict__ rv,
                         const float* __restrict__ b, int n,
                         float* __restrict__ scale, float* __restrict__ shift) {
  int i = blockIdx.x * blockDim.x + threadIdx.x;
  if (i < n) {
    float s = g[i] * rsqrtf(rv[i] + 1e-5f);
    scale[i] = s;
    shift[i] = (b[i] - rm[i]) * s + beta[i];
  }
}

__global__ void k_edge_count(const int* __restrict__ dst, int E, int* __restrict__ cnt) {
  int i = blockIdx.x * blockDim.x + threadIdx.x;
  if (i < E) atomicAdd(&cnt[dst[i]], 1);
}

__global__ void k_dinv(const int* __restrict__ cnt, int n, float* __restrict__ dinv) {
  int i = blockIdx.x * blockDim.x + threadIdx.x;
  if (i < n) dinv[i] = rsqrtf(1.0f + (float)cnt[i]);
}

// W [K][N] f32 -> Wt [N][Kp] bf16 (zero-padded K..Kp)
__global__ void k_wt(const float* __restrict__ W, int K, int N, int Kp,
                     unsigned short* __restrict__ Wt) {
  int idx = blockIdx.x * blockDim.x + threadIdx.x;
  if (idx >= N * Kp) return;
  int n = idx / Kp, k = idx - n * Kp;
  Wt[idx] = f2b(k < K ? W[(size_t)k * N + n] : 0.0f);
}

// x f32 [n][74] -> xb bf16 [n][80], PRE-SCALED by dinv[row] (norm folding)
__global__ void k_x2b(const float* __restrict__ x, const float* __restrict__ dinv, int n,
                      unsigned short* __restrict__ xb) {
  int idx = blockIdx.x * blockDim.x + threadIdx.x;
  if (idx >= n * 20) return;
  int row = idx / 20, j = idx - row * 20;
  int f0 = j * 4;
  float dv = dinv[row];
  ushort4v o;
#pragma unroll
  for (int j2 = 0; j2 < 4; ++j2) {
    int f = f0 + j2;
    o[j2] = (f < 74) ? f2b(dv * x[(size_t)row * 74 + f]) : (unsigned short)0;
  }
  *(ushort4v*)(xb + (size_t)row * 80 + f0) = o;
}

// graph boundaries (batch sorted)
__global__ void k_gbounds(const int* __restrict__ batch, int n, int* __restrict__ gstart,
                          int* __restrict__ gend) {
  int i = blockIdx.x * blockDim.x + threadIdx.x;
  if (i >= n) return;
  int g = batch[i];
  if (i == 0 || batch[i - 1] != g) gstart[g] = i;
  if (i == n - 1 || batch[i + 1] != g) gend[g] = i + 1;
}

// ---------------- exclusive scan (3 kernels) ----------------
__global__ void k_chunk_sum(const int* __restrict__ cnt, int n, int* __restrict__ bsum) {
  __shared__ int s[256];
  int base = blockIdx.x * SCAN_CHUNK;
  int t = threadIdx.x;
  int v = 0;
  for (int i = t; i < SCAN_CHUNK; i += 256) {
    int idx = base + i;
    v += (idx < n) ? cnt[idx] : 0;
  }
  s[t] = v;
  __syncthreads();
  for (int o = 128; o > 0; o >>= 1) {
    if (t < o) s[t] += s[t + o];
    __syncthreads();
  }
  if (t == 0) bsum[blockIdx.x] = s[0];
}

__global__ void k_scan_bsum(int* __restrict__ bsum, int nb) {
  if (threadIdx.x == 0 && blockIdx.x == 0) {
    int acc = 0;
    for (int i = 0; i < nb; ++i) { int v = bsum[i]; bsum[i] = acc; acc += v; }
  }
}

__global__ void k_write_rowptr(const int* __restrict__ cnt, int n, const int* __restrict__ bsum,
                               int* __restrict__ rowptr, int E) {
  __shared__ int s[256];
  __shared__ int sx[257];
  int base = blockIdx.x * SCAN_CHUNK;
  int t = threadIdx.x;
  int loc[4];
  int sum = 0;
#pragma unroll
  for (int j = 0; j < 4; ++j) {
    int idx = base + t * 4 + j;
    int c = (idx < n) ? cnt[idx] : 0;
    loc[j] = sum;
    sum += c;
  }
  s[t] = sum;
  __syncthreads();
  if (t == 0) {
    int acc = 0;
    for (int i = 0; i < 256; ++i) { sx[i] = acc; acc += s[i]; }
  }
  __syncthreads();
  int off = bsum[blockIdx.x] + sx[t];
#pragma unroll
  for (int j = 0; j < 4; ++j) {
    int idx = base + t * 4 + j;
    if (idx < n) rowptr[idx] = off + loc[j];
  }
  if (blockIdx.x == 0 && t == 0) rowptr[n] = E;
}

// CSR payload = src index only (4B scatter per edge; weights are folded)
__global__ void k_fill(const int* __restrict__ src, const int* __restrict__ dst, int E,
                       const int* __restrict__ rowptr, int* __restrict__ cursor,
                       int* __restrict__ colA) {
  int e = blockIdx.x * blockDim.x + threadIdx.x;
  if (e < E) {
    int d = dst[e];
    int p = atomicAdd(&cursor[d], 1);
    colA[rowptr[d] + p] = src[e];
  }
}

// ---------------- aggregation ----------------
// layer 1: xb bf16 [n][80] (pre-scaled) -> agg bf16 [n][128].
// One wave per node; each HALF-wave (lanes 0-19) gathers edges; pure sums.
__global__ __launch_bounds__(256) void k_aggregate74b(const unsigned short* __restrict__ xb,
                                                      const int* __restrict__ rowptr,
                                                      const int* __restrict__ colA,
                                                      const float* __restrict__ dinv, int n,
                                                      unsigned short* __restrict__ out) {
  int wid = (int)((blockIdx.x * (size_t)blockDim.x + threadIdx.x) >> 6);
  int lane = threadIdx.x & 63;
  if (wid >= n) return;
  int half = lane >> 5, hl = lane & 31;
  bool act = hl < 20;
  float acc[4] = {0.0f, 0.0f, 0.0f, 0.0f};
  int e0 = rowptr[wid], e1 = rowptr[wid + 1];
  int e = e0;
  for (; e + 7 < e1; e += 8) {
    int b = e + half * 4;
    int s0 = colA[b], s1 = colA[b + 1], s2 = colA[b + 2], s3 = colA[b + 3];
    ushort4v v0 = {}, v1 = {}, v2 = {}, v3 = {};
    if (act) {
      v0 = *(const ushort4v*)(xb + (size_t)s0 * 80 + hl * 4);
      v1 = *(const ushort4v*)(xb + (size_t)s1 * 80 + hl * 4);
      v2 = *(const ushort4v*)(xb + (size_t)s2 * 80 + hl * 4);
      v3 = *(const ushort4v*)(xb + (size_t)s3 * 80 + hl * 4);
    }
#pragma unroll
    for (int j = 0; j < 4; ++j)
      acc[j] += (b2f(v0[j]) + b2f(v1[j])) + (b2f(v2[j]) + b2f(v3[j]));
  }
  for (int t = e + half; t < e1; t += 2) {
    int s = colA[t];
    ushort4v v = {};
    if (act) v = *(const ushort4v*)(xb + (size_t)s * 80 + hl * 4);
#pragma unroll
    for (int j = 0; j < 4; ++j) acc[j] += b2f(v[j]);
  }
  // combine the two halves (all 64 lanes participate)
#pragma unroll
  for (int j = 0; j < 4; ++j) acc[j] += __shfl_xor(acc[j], 32);
  if (half == 0) {
    float di = dinv[wid];
    if (act) {
      ushort4v sv = *(const ushort4v*)(xb + (size_t)wid * 80 + hl * 4);  // self (pre-scaled)
      ushort4v o;
#pragma unroll
      for (int j = 0; j < 4; ++j) o[j] = f2b(di * (acc[j] + b2f(sv[j])));
      *(ushort4v*)(out + (size_t)wid * 128 + hl * 4) = o;
    } else {
      ushort4v z = {};
      *(ushort4v*)(out + (size_t)wid * 128 + 80 + (hl - 20) * 4) = z;  // zero 80..127
    }
  }
}

// F=256: h' fp8 e4m3 in (pre-scaled by dinv), bf16 agg out. 4B/lane gathers.
__global__ __launch_bounds__(256) void k_aggregate256(const unsigned char* __restrict__ h8,
                                                      const int* __restrict__ rowptr,
                                                      const int* __restrict__ colA,
                                                      const float* __restrict__ dinv, int n,
                                                      unsigned short* __restrict__ out) {
  int wid = (int)((blockIdx.x * (size_t)blockDim.x + threadIdx.x) >> 6);
  int lane = threadIdx.x & 63;
  if (wid >= n) return;
  float acc[4];
  {
    unsigned w = *(const unsigned*)(h8 + (size_t)wid * 256 + lane * 4);  // self term
    fp8x4_to_f32(w, acc);
  }
  int e0 = rowptr[wid], e1 = rowptr[wid + 1];
  int e = e0;
  for (; e + 7 < e1; e += 8) {
    int c[8];
    unsigned w[8];
#pragma unroll
    for (int q = 0; q < 8; ++q) c[q] = colA[e + q];
#pragma unroll
    for (int q = 0; q < 8; ++q)
      w[q] = *(const unsigned*)(h8 + (size_t)c[q] * 256 + lane * 4);
#pragma unroll
    for (int q = 0; q < 8; ++q) {
      float v[4];
      fp8x4_to_f32(w[q], v);
#pragma unroll
      for (int j = 0; j < 4; ++j) acc[j] += v[j];
    }
  }
  for (; e < e1; ++e) {
    unsigned w = *(const unsigned*)(h8 + (size_t)colA[e] * 256 + lane * 4);
    float v[4];
    fp8x4_to_f32(w, v);
#pragma unroll
    for (int j = 0; j < 4; ++j) acc[j] += v[j];
  }
  float di = dinv[wid];
  ushort4v o;
#pragma unroll
  for (int j = 0; j < 4; ++j) o[j] = f2b(di * acc[j]);
  *(ushort4v*)(out + (size_t)wid * 256 + lane * 4) = o;
}

// ---------------- bf16 MFMA GEMM ----------------
// A [M][K] bf16, Bt [N][K] bf16. 128x64 tile, 4 waves 2x2, mfma 16x16x32.
// EPI 0: fp8(dinv[row]*relu(v*scale+shift)) -> C8 ; EPI 1: bf16(v+shift) -> C16
template <int EPI>
__global__ __launch_bounds__(256) void k_gemm_mfma(const unsigned short* __restrict__ A,
                                                   const unsigned short* __restrict__ Bt,
                                                   int M, int N, int K,
                                                   const float* __restrict__ scale,
                                                   const float* __restrict__ shift,
                                                   const float* __restrict__ dinv,
                                                   unsigned char* __restrict__ C8,
                                                   unsigned short* __restrict__ C16) {
  __shared__ __align__(16) unsigned short Ast[128 * 64];
  __shared__ __align__(16) unsigned short Bst[64 * 64];
  const int t = threadIdx.x;
  const int lane = t & 63;
  const int wid = t >> 6;
  const int wm = wid >> 1, wn = wid & 1;
  const int lr = lane >> 4, lc = lane & 15;
  const int m0 = blockIdx.y * 128;
  const int n0 = blockIdx.x * 64;
  f32x4 acc[4][2] = {};
  char* astB = (char*)Ast;
  char* bstB = (char*)Bst;

  for (int kb = 0; kb < K; kb += 64) {
#pragma unroll
    for (int i = 0; i < 4; ++i) {
      int c = t + 256 * i;
      int row = c >> 3, slot = c & 7;
      int gm = m0 + row;
      ushort8v v = {};
      if (gm < M) v = *(const ushort8v*)(A + (size_t)gm * K + kb + slot * 8);
      int byte = row * 128 + slot * 16;
      *(ushort8v*)(astB + (byte ^ ((row & 7) << 4))) = v;
    }
#pragma unroll
    for (int i = 0; i < 2; ++i) {
      int c = t + 256 * i;
      int row = c >> 3, slot = c & 7;
      ushort8v v = *(const ushort8v*)(Bt + (size_t)(n0 + row) * K + kb + slot * 8);
      int byte = row * 128 + slot * 16;
      *(ushort8v*)(bstB + (byte ^ ((row & 7) << 4))) = v;
    }
    __syncthreads();
#pragma unroll
    for (int kk = 0; kk < 2; ++kk) {
      bf16x8 a[4], b[2];
      int kbyte = lr * 16 + kk * 64;
#pragma unroll
      for (int mi = 0; mi < 4; ++mi) {
        int row = wm * 64 + mi * 16 + lc;
        int byte = row * 128 + kbyte;
        a[mi] = *(const bf16x8*)(astB + (byte ^ ((row & 7) << 4)));
      }
#pragma unroll
      for (int ni = 0; ni < 2; ++ni) {
        int row = wn * 32 + ni * 16 + lc;
        int byte = row * 128 + kbyte;
        b[ni] = *(const bf16x8*)(bstB + (byte ^ ((row & 7) << 4)));
      }
#pragma unroll
      for (int mi = 0; mi < 4; ++mi)
#pragma unroll
        for (int ni = 0; ni < 2; ++ni)
          acc[mi][ni] =
              __builtin_amdgcn_mfma_f32_16x16x32_bf16(a[mi], b[ni], acc[mi][ni], 0, 0, 0);
    }
    __syncthreads();
  }

  // epilogue: D row=(lane>>4)*4+reg, col=lane&15
#pragma unroll
  for (int ni = 0; ni < 2; ++ni) {
    int colx = n0 + wn * 32 + ni * 16 + lc;
    float sc = (EPI == 0) ? scale[colx] : 0.0f;
    float sh = shift[colx];
#pragma unroll
    for (int mi = 0; mi < 4; ++mi) {
      int rbase = m0 + wm * 64 + mi * 16 + lr * 4;
#pragma unroll
      for (int r = 0; r < 4; ++r) {
        int row = rbase + r;
        if (row < M) {
          float v = acc[mi][ni][r];
          if (EPI == 0) {
            v = fmaxf(fmaf(v, sc, sh), 0.0f) * dinv[row];
            C8[(size_t)row * N + colx] = f32_to_fp8(v);
          } else {
            v += sh;
            C16[(size_t)row * N + colx] = f2b(v);
          }
        }
      }
    }
  }
}

// ---------------- pooling: one block per graph, no atomics ----------------
__global__ __launch_bounds__(384) void k_pool(const unsigned short* __restrict__ h3,
                                              const int* __restrict__ gstart,
                                              const int* __restrict__ gend, int NF,
                                              float* __restrict__ out) {
  int g = blockIdx.x;
  int t = threadIdx.x;  // 0..383, one column each
  int s = gstart[g], e = gend[g];
  if (s >= 0 && e > s) {
    float sum = 0.0f, mx = -3.4e38f;
    for (int r = s; r < e; ++r) {
      float v = b2f(h3[(size_t)r * NF + t]);
      sum += v;
      mx = fmaxf(mx, v);
    }
    out[(size_t)g * NF + t] = sum / (float)(e - s) + mx;
  } else {
    out[(size_t)g * NF + t] = -INFINITY;
  }
}

// ---------------- host launch ----------------
extern "C" void kernel_launch(void* const* d_in, const int* in_sizes, int n_in, void* d_out,
                              int out_size, void* d_ws, size_t ws_size, hipStream_t stream) {
  const float* x    = (const float*)d_in[0];
  const int* edge   = (const int*)d_in[1];
  const int* batch  = (const int*)d_in[2];
  const float* W1   = (const float*)d_in[3];
  const float* b1   = (const float*)d_in[4];
  const float* g1   = (const float*)d_in[5];
  const float* be1  = (const float*)d_in[6];
  const float* rm1  = (const float*)d_in[7];
  const float* rv1  = (const float*)d_in[8];
  const float* W2   = (const float*)d_in[9];
  const float* b2   = (const float*)d_in[10];
  const float* g2   = (const float*)d_in[11];
  const float* be2  = (const float*)d_in[12];
  const float* rm2  = (const float*)d_in[13];
  const float* rv2  = (const float*)d_in[14];
  const float* W3   = (const float*)d_in[15];
  const float* b3   = (const float*)d_in[16];

  const int NN = in_sizes[2];       // 100000
  const int E  = in_sizes[1] / 2;   // 1600000
  const int F1 = in_sizes[4];       // 256
  const int F3 = in_sizes[16];      // 384
  const int NG = out_size / F3;     // 2048
  const int K1p = 128;              // padded K for layer 1 (74 -> 128)
  const int* srcv = edge;
  const int* dstv = edge + E;

  char* p = (char*)d_ws;
  auto carve = [&](size_t bytes) -> char* {
    char* r = p;
    p += (bytes + 255) & ~(size_t)255;
    return r;
  };
  float* dinv           = (float*)carve((size_t)NN * 4);
  int* cnt              = (int*)carve((size_t)NN * 4);
  int* rowptr           = (int*)carve((size_t)(NN + 1) * 4);
  int* cursor           = (int*)carve((size_t)NN * 4);
  int* bsum             = (int*)carve(4096);
  int* colA             = (int*)carve((size_t)E * 4);
  float* scale1         = (float*)carve((size_t)F1 * 4);
  float* shift1         = (float*)carve((size_t)F1 * 4);
  float* scale2         = (float*)carve((size_t)F1 * 4);
  float* shift2         = (float*)carve((size_t)F1 * 4);
  unsigned short* W1t   = (unsigned short*)carve((size_t)F1 * K1p * 2);
  unsigned short* W2t   = (unsigned short*)carve((size_t)F1 * F1 * 2);
  unsigned short* W3t   = (unsigned short*)carve((size_t)F3 * F1 * 2);
  int* gstart           = (int*)carve((size_t)NG * 4);
  int* gend             = (int*)carve((size_t)NG * 4);
  unsigned short* xb    = (unsigned short*)carve((size_t)NN * 80 * 2);
  unsigned char* h8     = (unsigned char*)carve((size_t)NN * F1);       // fp8 h'
  unsigned short* agg   = (unsigned short*)carve((size_t)NN * F1 * 2);  // bf16 GEMM A
  unsigned short* h3    = (unsigned short*)carve((size_t)NN * F3 * 2);
  (void)ws_size; (void)n_in;

  // init
  hipMemsetAsync(cnt, 0, (size_t)NN * 4, stream);
  hipMemsetAsync(cursor, 0, (size_t)NN * 4, stream);
  hipMemsetAsync(gstart, 0xFF, (size_t)NG * 4, stream);
  hipMemsetAsync(gend, 0, (size_t)NG * 4, stream);
  k_bnprep<<<1, 256, 0, stream>>>(g1, be1, rm1, rv1, b1, F1, scale1, shift1);
  k_bnprep<<<1, 256, 0, stream>>>(g2, be2, rm2, rv2, b2, F1, scale2, shift2);
  k_wt<<<(F1 * K1p + 255) / 256, 256, 0, stream>>>(W1, 74, F1, K1p, W1t);
  k_wt<<<(F1 * F1 + 255) / 256, 256, 0, stream>>>(W2, F1, F1, F1, W2t);
  k_wt<<<(F3 * F1 + 255) / 256, 256, 0, stream>>>(W3, F1, F3, F1, W3t);
  k_gbounds<<<(NN + 255) / 256, 256, 0, stream>>>(batch, NN, gstart, gend);

  // degrees -> dinv (needed before x2b: norm folding)
  k_edge_count<<<(E + 255) / 256, 256, 0, stream>>>(dstv, E, cnt);
  k_dinv<<<(NN + 255) / 256, 256, 0, stream>>>(cnt, NN, dinv);
  k_x2b<<<(NN * 20 + 255) / 256, 256, 0, stream>>>(x, dinv, NN, xb);

  // CSR build (col-only payload)
  int nchunks = (NN + SCAN_CHUNK - 1) / SCAN_CHUNK;
  k_chunk_sum<<<nchunks, 256, 0, stream>>>(cnt, NN, bsum);
  k_scan_bsum<<<1, 64, 0, stream>>>(bsum, nchunks);
  k_write_rowptr<<<nchunks, 256, 0, stream>>>(cnt, NN, bsum, rowptr, E);
  k_fill<<<(E + 255) / 256, 256, 0, stream>>>(srcv, dstv, E, rowptr, cursor, colA);

  dim3 blk(256);
  int aggBlocks = (NN + 3) / 4;
  int gy = (NN + 127) / 128;

  // Layer 1: agg(xb') -> bf16 [NN][128]; GEMM + bn1 + relu + dinv-fold -> h8 (fp8)
  k_aggregate74b<<<aggBlocks, blk, 0, stream>>>(xb, rowptr, colA, dinv, NN, agg);
  {
    dim3 grid(F1 / 64, gy);
    k_gemm_mfma<0><<<grid, blk, 0, stream>>>(agg, W1t, NN, F1, K1p, scale1, shift1, dinv,
                                             h8, nullptr);
  }
  // Layer 2
  k_aggregate256<<<aggBlocks, blk, 0, stream>>>(h8, rowptr, colA, dinv, NN, agg);
  {
    dim3 grid(F1 / 64, gy);
    k_gemm_mfma<0><<<grid, blk, 0, stream>>>(agg, W2t, NN, F1, F1, scale2, shift2, dinv,
                                             h8, nullptr);
  }
  // Layer 3: agg -> GEMM + bias -> h3 bf16; then per-graph pool
  k_aggregate256<<<aggBlocks, blk, 0, stream>>>(h8, rowptr, colA, dinv, NN, agg);
  {
    dim3 grid(F3 / 64, gy);
    k_gemm_mfma<1><<<grid, blk, 0, stream>>>(agg, W3t, NN, F3, F1, nullptr, b3, dinv,
                                             nullptr, h3);
  }
  k_pool<<<NG, 384, 0, stream>>>(h3, gstart, gend, F3, (float*)d_out);
}